// Round 14
// baseline (1039.942 us; speedup 1.0000x reference)
//
#include <hip/hip_runtime.h>

#define L_  6
#define E_  384
#define T_  256
#define H_  6
#define D_  64
#define V_  65
#define FF_ 1536
#define B_  64
#define BT_ (B_*T_)    // 16384 rows
#define HD_ 384

typedef __attribute__((ext_vector_type(8))) short short8;
typedef __attribute__((ext_vector_type(4))) float f32x4;
typedef unsigned short us;
typedef unsigned int u32;

__device__ __forceinline__ us f2bf(float f) {
  u32 u = __float_as_uint(f);
  u32 r = (u + 0x7fffu + ((u >> 16) & 1u)) >> 16;  // RNE
  return (us)r;
}
__device__ __forceinline__ float bf2f(us v) {
  return __uint_as_float(((u32)v) << 16);
}

// XCD-chunked bijective block remap (requires gridDim.x % 8 == 0).
__device__ __forceinline__ int xcd_swz(int b, int nwg) {
  const int q = nwg >> 3;
  return (b & 7) * q + (b >> 3);
}

// ---------------------------------------------------------------------------
// Embedding: h[b,t,:] = tok_emb[x[b,t]] + pos_emb[t]  -> bf16
// ---------------------------------------------------------------------------
__global__ void embed_kernel(const int* __restrict__ x, const float* __restrict__ tok,
                             const float* __restrict__ pos, us* __restrict__ h) {
  const int total8 = BT_ * E_ / 8;
  for (int i = blockIdx.x * blockDim.x + threadIdx.x; i < total8;
       i += gridDim.x * blockDim.x) {
    const int flat = i << 3;
    const int row  = flat / E_;
    const int e    = flat - row * E_;
    const int id   = x[row];
    const float4 a0 = *reinterpret_cast<const float4*>(tok + id * E_ + e);
    const float4 a1 = *reinterpret_cast<const float4*>(tok + id * E_ + e + 4);
    const float4 p0 = *reinterpret_cast<const float4*>(pos + (row & (T_ - 1)) * E_ + e);
    const float4 p1 = *reinterpret_cast<const float4*>(pos + (row & (T_ - 1)) * E_ + e + 4);
    short8 o;
    o[0] = (short)f2bf(a0.x + p0.x); o[1] = (short)f2bf(a0.y + p0.y);
    o[2] = (short)f2bf(a0.z + p0.z); o[3] = (short)f2bf(a0.w + p0.w);
    o[4] = (short)f2bf(a1.x + p1.x); o[5] = (short)f2bf(a1.y + p1.y);
    o[6] = (short)f2bf(a1.z + p1.z); o[7] = (short)f2bf(a1.w + p1.w);
    *reinterpret_cast<short8*>(h + flat) = o;
  }
}

// ---------------------------------------------------------------------------
// Row stats: st[row] = (mean, 1/sqrt(var+eps)). One wave per row.
// ---------------------------------------------------------------------------
template<int DDOF>
__global__ void stats_kernel(const us* __restrict__ h, float2* __restrict__ st) {
  const int wave = threadIdx.x >> 6;
  const int lane = threadIdx.x & 63;
  const int row  = (blockIdx.x << 2) + wave;
  float sum = 0.f, sq = 0.f;
  if (lane < 48) {
    const short8 v = *reinterpret_cast<const short8*>(h + (size_t)row * E_ + lane * 8);
#pragma unroll
    for (int j = 0; j < 8; ++j) {
      const float f = bf2f((us)v[j]);
      sum += f; sq += f * f;
    }
  }
#pragma unroll
  for (int off = 32; off > 0; off >>= 1) {
    sum += __shfl_xor(sum, off);
    sq  += __shfl_xor(sq, off);
  }
  if (lane == 0) {
    const float mean = sum * (1.f / E_);
    const float var  = (sq - E_ * mean * mean) * (1.f / (E_ - DDOF));
    float2 o; o.x = mean; o.y = rsqrtf(var + 1e-5f);
    st[row] = o;
  }
}

// ---------------------------------------------------------------------------
// Weight transpose + optional g-scale + fp32->bf16:
// dst[n][k] = g[k]*src[k][n], zero-pad n in [N,Ndst). g==nullptr -> 1.
// ---------------------------------------------------------------------------
__global__ void transpose_w(const float* __restrict__ src, us* __restrict__ dst,
                            int K, int N, int Ndst, long srcLS, long dstLS,
                            const float* __restrict__ g) {
  __shared__ float t[32][33];
  const int n0 = blockIdx.x << 5, k0 = blockIdx.y << 5;
  const int tx = threadIdx.x & 31, ty = threadIdx.x >> 5;
  const float* s = src + (size_t)blockIdx.z * srcLS;
  us* d = dst + (size_t)blockIdx.z * dstLS;
#pragma unroll
  for (int j = 0; j < 32; j += 8) {
    const int n = n0 + tx;
    t[ty + j][tx] = (n < N) ? s[(size_t)(k0 + ty + j) * N + n] : 0.f;
  }
  __syncthreads();
  const float gk = g ? g[blockIdx.z * 384 + k0 + tx] : 1.f;
#pragma unroll
  for (int j = 0; j < 32; j += 8) {
    const int n = n0 + ty + j;
    if (n < Ndst) d[(size_t)n * K + k0 + tx] = f2bf(t[tx][ty + j] * gk);
  }
}

// ---------------------------------------------------------------------------
// QKV transpose (one launch for Wq/Wk/Wv x 6 layers): z in [0,18).
// ---------------------------------------------------------------------------
__global__ void transpose_qkv(const float* __restrict__ Wq, const float* __restrict__ Wk,
                              const float* __restrict__ Wv, us* __restrict__ dst,
                              const float* __restrict__ g) {
  __shared__ float t[32][33];
  const int sel = blockIdx.z / 6, l = blockIdx.z % 6;
  const float* s = (sel == 0 ? Wq : sel == 1 ? Wk : Wv) + (size_t)l * 147456;
  us* d = dst + (size_t)l * 442368 + sel * 147456;
  const int n0 = blockIdx.x << 5, k0 = blockIdx.y << 5;
  const int tx = threadIdx.x & 31, ty = threadIdx.x >> 5;
#pragma unroll
  for (int j = 0; j < 32; j += 8)
    t[ty + j][tx] = s[(size_t)(k0 + ty + j) * 384 + n0 + tx];
  __syncthreads();
  const float gk = g[l * 384 + k0 + tx];
#pragma unroll
  for (int j = 0; j < 32; j += 8)
    d[(size_t)(n0 + ty + j) * 384 + k0 + tx] = f2bf(t[tx][ty + j] * gk);
}

// ---------------------------------------------------------------------------
// c1[n] = sum_k g[k]*W[k][n]; c2[n] = sum_k b[k]*W[k][n]  (fp32, K=384)
// ---------------------------------------------------------------------------
__global__ void c12_kernel(const float* __restrict__ W, const float* __restrict__ g,
                           const float* __restrict__ b, float2* __restrict__ out,
                           int N, long srcLS, int outLS) {
  __shared__ float p1[4][64], p2[4][64];
  const int t = threadIdx.x;
  const int c = t & 63, kq = t >> 6;
  const int n = (blockIdx.x << 6) + c;
  const float* Wz = W + (size_t)blockIdx.y * srcLS;
  const float* gz = g + blockIdx.y * 384;
  const float* bz = b + blockIdx.y * 384;
  float s1 = 0.f, s2 = 0.f;
  if (n < N) {
    for (int k = kq * 96; k < kq * 96 + 96; ++k) {
      const float w = Wz[(size_t)k * N + n];
      s1 = fmaf(gz[k], w, s1);
      s2 = fmaf(bz[k], w, s2);
    }
  }
  p1[kq][c] = s1; p2[kq][c] = s2;
  __syncthreads();
  if (t < 64) {
    const int nn = (blockIdx.x << 6) + t;
    if (nn < N) {
      float2 o;
      o.x = p1[0][t] + p1[1][t] + p1[2][t] + p1[3][t];
      o.y = p2[0][t] + p2[1][t] + p2[2][t] + p2[3][t];
      out[(size_t)blockIdx.y * outLS + nn] = o;
    }
  }
}

// ---------------------------------------------------------------------------
// c12 for QKV in one launch: blockIdx.y in [0,18) -> (sel, layer).
// ---------------------------------------------------------------------------
__global__ void c12_qkv(const float* __restrict__ Wq, const float* __restrict__ Wk,
                        const float* __restrict__ Wv, const float* __restrict__ g,
                        const float* __restrict__ b, float2* __restrict__ out) {
  __shared__ float p1[4][64], p2[4][64];
  const int sel = blockIdx.y / 6, l = blockIdx.y % 6;
  const float* Wz = (sel == 0 ? Wq : sel == 1 ? Wk : Wv) + (size_t)l * 147456;
  const float* gz = g + l * 384;
  const float* bz = b + l * 384;
  const int t = threadIdx.x;
  const int c = t & 63, kq = t >> 6;
  const int n = (blockIdx.x << 6) + c;
  float s1 = 0.f, s2 = 0.f;
  for (int k = kq * 96; k < kq * 96 + 96; ++k) {
    const float w = Wz[(size_t)k * 384 + n];
    s1 = fmaf(gz[k], w, s1);
    s2 = fmaf(bz[k], w, s2);
  }
  p1[kq][c] = s1; p2[kq][c] = s2;
  __syncthreads();
  if (t < 64) {
    const int nn = (blockIdx.x << 6) + t;
    float2 o;
    o.x = p1[0][t] + p1[1][t] + p1[2][t] + p1[3][t];
    o.y = p2[0][t] + p2[1][t] + p2[2][t] + p2[3][t];
    out[(size_t)l * 1152 + sel * 384 + nn] = o;
  }
}

// ---------------------------------------------------------------------------
// Async global->LDS staging of a ROWS x (CHPR*8 us) bf16 tile. LDS dest is
// linear; XOR chunk swizzle applied on the GLOBAL source side (rule #21).
// ---------------------------------------------------------------------------
template<int ROWS, int CHPR, int NTH>
__device__ __forceinline__ void stageG(const us* g, int rowUs, us* lds, int tid) {
#pragma unroll
  for (int j = 0; j < ROWS * CHPR / NTH; ++j) {
    const int fl  = j * NTH + tid;
    const int row = fl / CHPR;
    const int c   = fl % CHPR;
    const int gc  = (CHPR == 8) ? (c ^ (row & 7)) : (c ^ ((row >> 1) & 3));
    const us* src = g + (size_t)row * rowUs + gc * 8;
    __builtin_amdgcn_global_load_lds(
        (const __attribute__((address_space(1))) u32*)src,
        (__attribute__((address_space(3))) u32*)(lds + ((fl >> 6) << 9)),
        16, 0, 0);
  }
}

// ---------------------------------------------------------------------------
// Shared K-loop machinery: tile (FM*32)x(FN*32), BK=32, 4 waves (2x2),
// BUFS-buffer / (BUFS-1)-deep prefetch, counted vmcnt, raw s_barrier.
// ---------------------------------------------------------------------------
#define GEMM_LOOP(K_, NT_)                                                        \
  const int NT = (NT_);                                                           \
  _Pragma("unroll")                                                               \
  for (int p = 0; p < BUFS - 1; ++p) {                                            \
    stageG<BM, 4, 256>(Abase + p * 32, (K_), As[p], tid);                         \
    stageG<BN, 4, 256>(Bbase + p * 32, (K_), Bs[p], tid);                         \
  }                                                                               \
  int cb = 0;                                                                     \
  for (int t = 0; t < NT; ++t) {                                                  \
    if constexpr (BUFS == 4) {                                                    \
      if (t < NT - 2)       asm volatile("s_waitcnt vmcnt(%0)" :: "n"(2 * LPS) : "memory"); \
      else if (t == NT - 2) asm volatile("s_waitcnt vmcnt(%0)" :: "n"(LPS) : "memory");     \
      else                  asm volatile("s_waitcnt vmcnt(0)" ::: "memory");      \
    } else {                                                                      \
      if (t < NT - 1)       asm volatile("s_waitcnt vmcnt(%0)" :: "n"(LPS) : "memory");     \
      else                  asm volatile("s_waitcnt vmcnt(0)" ::: "memory");      \
    }                                                                             \
    __builtin_amdgcn_s_barrier();                                                 \
    __builtin_amdgcn_sched_barrier(0);                                            \
    if (t + BUFS - 1 < NT) {                                                      \
      int ib = cb + (BUFS - 1); if (ib >= BUFS) ib -= BUFS;                       \
      stageG<BM, 4, 256>(Abase + (t + BUFS - 1) * 32, (K_), As[ib], tid);         \
      stageG<BN, 4, 256>(Bbase + (t + BUFS - 1) * 32, (K_), Bs[ib], tid);         \
    }                                                                             \
    short8 af[FM], bfr[FN];                                                       \
    _Pragma("unroll")                                                             \
    for (int mt = 0; mt < FM; ++mt) {                                             \
      const int row = wm + mt * 16 + fm;                                          \
      af[mt] = *(const short8*)(As[cb] + row * 32 + ((fg ^ ((row >> 1) & 3)) << 3)); \
    }                                                                             \
    _Pragma("unroll")                                                             \
    for (int nt = 0; nt < FN; ++nt) {                                             \
      const int row = wn + nt * 16 + fm;                                          \
      bfr[nt] = *(const short8*)(Bs[cb] + row * 32 + ((fg ^ ((row >> 1) & 3)) << 3)); \
    }                                                                             \
    _Pragma("unroll")                                                             \
    for (int mt = 0; mt < FM; ++mt)                                               \
      _Pragma("unroll")                                                           \
      for (int nt = 0; nt < FN; ++nt)                                             \
        acc[mt][nt] = __builtin_amdgcn_mfma_f32_16x16x32_bf16(af[mt], bfr[nt], acc[mt][nt], 0, 0, 0); \
    cb = (cb + 1 == BUFS) ? 0 : cb + 1;                                           \
  }

// ---------------------------------------------------------------------------
// Plain MFMA GEMM, epilogue = +bias +Res(bf16) -> bf16.  (proj, FF2)
// ---------------------------------------------------------------------------
template<int FM, int FN, int BUFS>
__global__ __launch_bounds__(256)
void gemm_mfma(const us* __restrict__ A, const us* __restrict__ Bt,
               const float* __restrict__ bias, const us* Res,
               us* __restrict__ O, int N, int K, int gx) {
  constexpr int BM = FM * 32, BN = FN * 32;
  constexpr int LPS = (BM + BN) * 4 / 256;
  __shared__ us As[BUFS][BM * 32];
  __shared__ us Bs[BUFS][BN * 32];
  const int tid = threadIdx.x;
  const int lid = xcd_swz(blockIdx.x, gridDim.x);
  const int bnI = lid % gx, bmI = lid / gx;
  const int bm = bmI * BM, bn = bnI * BN;
  const int wv = tid >> 6, ln = tid & 63;
  const int fm = ln & 15, fg = ln >> 4;
  const int wm = (wv >> 1) * (FM * 16), wn = (wv & 1) * (FN * 16);
  const us* Abase = A + (size_t)bm * K;
  const us* Bbase = Bt + (size_t)bn * K;

  f32x4 acc[FM][FN];
  const f32x4 zz = {0.f, 0.f, 0.f, 0.f};
#pragma unroll
  for (int i = 0; i < FM; ++i)
#pragma unroll
    for (int j = 0; j < FN; ++j) acc[i][j] = zz;

  GEMM_LOOP(K, K >> 5)

#pragma unroll
  for (int mt = 0; mt < FM; ++mt) {
#pragma unroll
    for (int nt = 0; nt < FN; ++nt) {
      const int col  = bn + wn + nt * 16 + fm;
      const int row0 = bm + wm + mt * 16 + fg * 4;
      const float bc = bias[col];
#pragma unroll
      for (int r = 0; r < 4; ++r) {
        const size_t idx = (size_t)(row0 + r) * N + col;
        O[idx] = f2bf(acc[mt][nt][r] + bc + bf2f(Res[idx]));
      }
    }
  }
}

// ---------------------------------------------------------------------------
// Folded-LN MFMA GEMM: A = raw h (bf16), Bt pre-scaled by g.
// out = inv*(acc - mu*c1[col]) + c2[col] (+bias).
// EPI: 0 = QKV split (q/k -> O0 [BT][768] bf16, v -> O1 [B*H][64][256] bf16)
//      2 = +bias +ReLU -> bf16 O0
//      3 = +bias, col<65 -> fp32 O0 stride 65 (LM head)
// ---------------------------------------------------------------------------
template<int FM, int FN, int EPI, int BUFS>
__global__ __launch_bounds__(256)
void gemm_fold(const us* __restrict__ A, const us* __restrict__ Bt,
               const float2* __restrict__ st, const float2* __restrict__ c12,
               const float* __restrict__ bias, void* O0, void* O1,
               int N, int gx) {
  constexpr int K = 384;
  constexpr int BM = FM * 32, BN = FN * 32;
  constexpr int LPS = (BM + BN) * 4 / 256;
  __shared__ us As[BUFS][BM * 32];
  __shared__ us Bs[BUFS][BN * 32];
  const int tid = threadIdx.x;
  const int lid = xcd_swz(blockIdx.x, gridDim.x);
  const int bnI = lid % gx, bmI = lid / gx;
  const int bm = bmI * BM, bn = bnI * BN;
  const int wv = tid >> 6, ln = tid & 63;
  const int fm = ln & 15, fg = ln >> 4;
  const int wm = (wv >> 1) * (FM * 16), wn = (wv & 1) * (FN * 16);
  const us* Abase = A + (size_t)bm * K;
  const us* Bbase = Bt + (size_t)bn * K;

  f32x4 acc[FM][FN];
  const f32x4 zz = {0.f, 0.f, 0.f, 0.f};
#pragma unroll
  for (int i = 0; i < FM; ++i)
#pragma unroll
    for (int j = 0; j < FN; ++j) acc[i][j] = zz;

  GEMM_LOOP(K, 12)

#pragma unroll
  for (int mt = 0; mt < FM; ++mt) {
    const int row0 = bm + wm + mt * 16 + fg * 4;
    float2 sr[4];
#pragma unroll
    for (int r = 0; r < 4; ++r) sr[r] = st[row0 + r];
#pragma unroll
    for (int nt = 0; nt < FN; ++nt) {
      const int col = bn + wn + nt * 16 + fm;
      if (EPI == 3 && col >= V_) continue;
      const float2 cc = c12[col];
      float vals[4];
#pragma unroll
      for (int r = 0; r < 4; ++r)
        vals[r] = sr[r].y * (acc[mt][nt][r] - sr[r].x * cc.x) + cc.y;
      if (EPI == 0) {
        if (col < 768) {
          us* qk = (us*)O0;
#pragma unroll
          for (int r = 0; r < 4; ++r)
            qk[(size_t)(row0 + r) * 768 + col] = f2bf(vals[r]);
        } else {                              // v -> transposed [B*H][64][256]
          const int d = col - 768;
          const int hh = d >> 6, dd = d & 63;
          const int bI = row0 >> 8, t0 = row0 & 255;
          us* vt = (us*)O1;
          ushort4 pk;
          pk.x = f2bf(vals[0]); pk.y = f2bf(vals[1]);
          pk.z = f2bf(vals[2]); pk.w = f2bf(vals[3]);
          *reinterpret_cast<ushort4*>(vt + ((size_t)((bI * H_ + hh) * 64 + dd)) * 256 + t0) = pk;
        }
      } else if (EPI == 2) {
        us* o = (us*)O0;
        const float bc = bias[col];
#pragma unroll
        for (int r = 0; r < 4; ++r)
          o[(size_t)(row0 + r) * N + col] = f2bf(fmaxf(vals[r] + bc, 0.f));
      } else {
        float* o = (float*)O0;
        const float bc = bias[col];
#pragma unroll
        for (int r = 0; r < 4; ++r)
          o[(size_t)(row0 + r) * V_ + col] = vals[r] + bc;
      }
    }
  }
}

// ---------------------------------------------------------------------------
// MFMA flash attention. Block = (b, h, 64-query tile); 4 waves x 16 queries.
// K/V tiles staged in LDS (double-buffered, issue-early 2-phase), CHPR=8
// XOR swizzle. qk: [BT][768] bf16; vT: [B*H][64][256] bf16; ab: [BT][384].
// ---------------------------------------------------------------------------
__global__ __launch_bounds__(256)
void attn_mfma(const us* __restrict__ qk, const us* __restrict__ vT,
               us* __restrict__ ab) {
  __shared__ us Ks[2][64 * 64];
  __shared__ us Vs[2][64 * 64];
  __shared__ us Plds[4][16 * 72];   // per-wave P tile, stride 72 (pad)
  const int tid = threadIdx.x, w = tid >> 6, l = tid & 63;
  const int m = l & 15, g = l >> 4;
  const int bi = xcd_swz(blockIdx.x, gridDim.x);
  const int b = bi / 24, rem = bi - b * 24, h = rem >> 2, qt = rem & 3;
  const int qrow = (b << 8) + (qt << 6) + (w << 4);
  const us* Kg = qk + (size_t)(b << 8) * 768 + 384 + h * 64;  // + kt*64 rows
  const us* Vg = vT + (size_t)(b * H_ + h) * 64 * 256;        // + kt*64 cols

  short8 qf0, qf1;
  {
    const us* qp = qk + (size_t)(qrow + m) * 768 + h * 64 + g * 8;
    qf0 = *(const short8*)qp;
    qf1 = *(const short8*)(qp + 32);
  }
  float mrow[4], ssum[4];
  f32x4 o[4];
  const f32x4 zz = {0.f, 0.f, 0.f, 0.f};
#pragma unroll
  for (int r = 0; r < 4; ++r) { mrow[r] = -1e30f; ssum[r] = 0.f; o[r] = zz; }

  stageG<64, 8, 256>(Kg, 768, Ks[0], tid);
  stageG<64, 8, 256>(Vg, 256, Vs[0], tid);
  __syncthreads();

  int cur = 0;
  for (int kt = 0; kt <= qt; ++kt) {
    if (kt < qt) {
      stageG<64, 8, 256>(Kg + (size_t)(kt + 1) * 64 * 768, 768, Ks[cur ^ 1], tid);
      stageG<64, 8, 256>(Vg + (kt + 1) * 64,               256, Vs[cur ^ 1], tid);
    }
    // ---- S = Q K^T (16 queries x 64 keys) from LDS ----
    f32x4 s[4];
#pragma unroll
    for (int nt = 0; nt < 4; ++nt) {
      const int row = nt * 16 + m;
      const int sw  = row & 7;
      short8 kf0 = *(const short8*)(Ks[cur] + row * 64 + ((g ^ sw) << 3));
      short8 kf1 = *(const short8*)(Ks[cur] + row * 64 + (((4 | g) ^ sw) << 3));
      f32x4 z = zz;
      z = __builtin_amdgcn_mfma_f32_16x16x32_bf16(qf0, kf0, z, 0, 0, 0);
      z = __builtin_amdgcn_mfma_f32_16x16x32_bf16(qf1, kf1, z, 0, 0, 0);
      s[nt] = z;
    }
    // ---- mask + online softmax ----
    const bool diag = (kt == qt);
    float p[4][4], tmax[4];
#pragma unroll
    for (int r = 0; r < 4; ++r) tmax[r] = -1e30f;
#pragma unroll
    for (int nt = 0; nt < 4; ++nt)
#pragma unroll
      for (int r = 0; r < 4; ++r) {
        float v = s[nt][r] * 0.125f;
        if (diag) {
          const int key = nt * 16 + m;
          const int qq  = (w << 4) + (g << 2) + r;
          if (key > qq) v = -1e30f;
        }
        p[nt][r] = v;
        tmax[r] = fmaxf(tmax[r], v);
      }
#pragma unroll
    for (int xm = 1; xm < 16; xm <<= 1)
#pragma unroll
      for (int r = 0; r < 4; ++r) tmax[r] = fmaxf(tmax[r], __shfl_xor(tmax[r], xm));
    float sc[4], tsum[4];
#pragma unroll
    for (int r = 0; r < 4; ++r) {
      const float nm = fmaxf(mrow[r], tmax[r]);
      sc[r] = __expf(mrow[r] - nm);
      mrow[r] = nm;
      tsum[r] = 0.f;
    }
#pragma unroll
    for (int nt = 0; nt < 4; ++nt)
#pragma unroll
      for (int r = 0; r < 4; ++r) {
        p[nt][r] = __expf(p[nt][r] - mrow[r]);
        tsum[r] += p[nt][r];
      }
#pragma unroll
    for (int xm = 1; xm < 16; xm <<= 1)
#pragma unroll
      for (int r = 0; r < 4; ++r) tsum[r] += __shfl_xor(tsum[r], xm);
#pragma unroll
    for (int r = 0; r < 4; ++r) ssum[r] = ssum[r] * sc[r] + tsum[r];
#pragma unroll
    for (int nt = 0; nt < 4; ++nt)
#pragma unroll
      for (int r = 0; r < 4; ++r) o[nt][r] *= sc[r];
    // ---- P -> LDS (bf16, C-layout -> A-layout transpose via LDS) ----
#pragma unroll
    for (int nt = 0; nt < 4; ++nt)
#pragma unroll
      for (int r = 0; r < 4; ++r)
        Plds[w][(g * 4 + r) * 72 + nt * 16 + m] = f2bf(p[nt][r]);
    // ---- O += P V (V from LDS) ----
#pragma unroll
    for (int kc = 0; kc < 2; ++kc) {
      short8 pa = *(const short8*)&Plds[w][m * 72 + kc * 32 + g * 8];
#pragma unroll
      for (int nd = 0; nd < 4; ++nd) {
        const int row = nd * 16 + m;
        short8 vf = *(const short8*)(Vs[cur] + row * 64 + ((((kc << 2) | g) ^ (row & 7)) << 3));
        o[nd] = __builtin_amdgcn_mfma_f32_16x16x32_bf16(pa, vf, o[nd], 0, 0, 0);
      }
    }
    __syncthreads();   // staged next tile arrived; all reads of cur done
    cur ^= 1;
  }
  // ---- normalize + write ----
#pragma unroll
  for (int r = 0; r < 4; ++r) {
    const float inv = 1.f / ssum[r];
    const size_t rowoff = (size_t)(qrow + g * 4 + r) * 384 + h * 64;
#pragma unroll
    for (int nd = 0; nd < 4; ++nd)
      ab[rowoff + nd * 16 + m] = f2bf(o[nd][r] * inv);
  }
}

// ---------------------------------------------------------------------------
extern "C" void kernel_launch(void* const* d_in, const int* in_sizes, int n_in,
                              void* d_out, int out_size, void* d_ws, size_t ws_size,
                              hipStream_t stream) {
  const int*   x    = (const int*)  d_in[0];
  const float* tok  = (const float*)d_in[1];
  const float* pos  = (const float*)d_in[2];
  const float* Wq   = (const float*)d_in[3];
  const float* Wk   = (const float*)d_in[4];
  const float* Wv   = (const float*)d_in[5];
  const float* Wpr  = (const float*)d_in[6];
  const float* bpr  = (const float*)d_in[7];
  const float* W1   = (const float*)d_in[8];
  const float* b1   = (const float*)d_in[9];
  const float* W2   = (const float*)d_in[10];
  const float* b2   = (const float*)d_in[11];
  const float* ln1g = (const float*)d_in[12];
  const float* ln1b = (const float*)d_in[13];
  const float* ln2g = (const float*)d_in[14];
  const float* ln2b = (const float*)d_in[15];
  const float* lnfg = (const float*)d_in[16];
  const float* lnfb = (const float*)d_in[17];
  const float* Wlm  = (const float*)d_in[18];
  const float* blm  = (const float*)d_in[19];
  float* out = (float*)d_out;

  char* W = (char*)d_ws;
  us*     h    = (us*)(W + 0);            // [BT][384] bf16       12.58 MB
  us*     qkb  = (us*)(W + 12582912);     // [BT][768] bf16       25.17 MB
  us*     vTb  = (us*)(W + 37748736);     // [B*H][64][256] bf16  12.58 MB
  us*     abb  = (us*)(W + 50331648);     // [BT][384] bf16       12.58 MB
  us*     ffa  = (us*)(W + 12582912);     // [BT][1536] bf16 (aliases qk+vT+ab)
  us*     qkvT = (us*)(W + 62914560);     // [L][1152][384] bf16 (g-scaled)
  us*     projT= (us*)(W + 68222976);     // [L][384][384]
  us*     W1T  = (us*)(W + 69992448);     // [L][1536][384] (g-scaled)
  us*     W2T  = (us*)(W + 77070336);     // [L][384][1536]
  us*     WlmT = (us*)(W + 84148224);     // [128][384] (g-scaled, rows 65+ zero)
  float2* st   = (float2*)(W + 84246528); // [BT] (mean, inv)     131 KB
  float2* c12q = (float2*)(W + 84377600); // [L][1152]
  float2* c12f = (float2*)(W + 84432896); // [L][1536]
  float2* c12lm= (float2*)(W + 84506624); // [65]

  // ---- weight conversion (g folded into B) + c1/c2 ----
  transpose_qkv<<<dim3(12,12,18), 256, 0, stream>>>(Wq, Wk, Wv, qkvT, ln1g);
  transpose_w<<<dim3(12,12,6), 256, 0, stream>>>(Wpr, projT, 384, 384, 384, 147456, 147456, nullptr);
  transpose_w<<<dim3(48,12,6), 256, 0, stream>>>(W1,  W1T,   384, 1536, 1536, 589824, 589824, ln2g);
  transpose_w<<<dim3(12,48,6), 256, 0, stream>>>(W2,  W2T,   1536, 384, 384, 589824, 589824, nullptr);
  transpose_w<<<dim3(4,12,1),  256, 0, stream>>>(Wlm, WlmT,  384, 65, 128, 0, 0, lnfg);

  c12_qkv<<<dim3(6,18), 256, 0, stream>>>(Wq, Wk, Wv, ln1g, ln1b, c12q);
  c12_kernel<<<dim3(24,6), 256, 0, stream>>>(W1,  ln2g, ln2b, c12f,  1536, 589824, 1536);
  c12_kernel<<<dim3(2,1),  256, 0, stream>>>(Wlm, lnfg, lnfb, c12lm, 65, 0, 0);

  embed_kernel<<<3072, 256, 0, stream>>>(x, tok, pos, h);

  for (int l = 0; l < L_; ++l) {
    stats_kernel<1><<<BT_/4, 256, 0, stream>>>(h, st);
    // QKV (folded LN1): 128x128 tiles, BUFS=4 (3-deep) -> 1152 blocks
    gemm_fold<4,4,0,4><<<1152, 256, 0, stream>>>(
        h, qkvT + (size_t)l*442368, st, c12q + (size_t)l*1152, nullptr,
        qkb, vTb, 1152, 9);
    attn_mfma<<<B_*H_*4, 256, 0, stream>>>(qkb, vTb, abb);
    // proj: 64x128 tiles, BUFS=4 -> 768 blocks
    gemm_mfma<2,4,4><<<768, 256, 0, stream>>>(
        abb, projT + (size_t)l*147456, bpr + l*E_, h, h, 384, 384, 3);
    stats_kernel<1><<<BT_/4, 256, 0, stream>>>(h, st);
    // FF1 (folded LN2): 128x128 tiles, BUFS=4 (3-deep) -> 1536 blocks
    gemm_fold<4,4,2,4><<<1536, 256, 0, stream>>>(
        h, W1T + (size_t)l*589824, st, c12f + (size_t)l*1536, b1 + l*FF_,
        ffa, nullptr, 1536, 12);
    // FF2: 128x128 tiles, K=1536, BUFS=4 (3-deep) -> 384 blocks
    gemm_mfma<4,4,4><<<384, 256, 0, stream>>>(
        ffa, W2T + (size_t)l*589824, b2 + l*E_, h, h, 384, 1536, 3);
  }

  stats_kernel<0><<<BT_/4, 256, 0, stream>>>(h, st);
  // LM head (folded LNf): 64x128 tiles, BUFS=4 -> 256 blocks
  gemm_fold<2,4,3,4><<<256, 256, 0, stream>>>(
      h, WlmT, st, c12lm, blm, out, nullptr, 128, 1);
}

// Round 15
// 917.662 us; speedup vs baseline: 1.1333x; 1.1333x over previous
//
#include <hip/hip_runtime.h>

#define L_  6
#define E_  384
#define T_  256
#define H_  6
#define D_  64
#define V_  65
#define FF_ 1536
#define B_  64
#define BT_ (B_*T_)    // 16384 rows
#define HD_ 384

typedef __attribute__((ext_vector_type(8))) short short8;
typedef __attribute__((ext_vector_type(4))) float f32x4;
typedef unsigned short us;
typedef unsigned int u32;

__device__ __forceinline__ us f2bf(float f) {
  u32 u = __float_as_uint(f);
  u32 r = (u + 0x7fffu + ((u >> 16) & 1u)) >> 16;  // RNE
  return (us)r;
}
__device__ __forceinline__ float bf2f(us v) {
  return __uint_as_float(((u32)v) << 16);
}

// XCD-chunked bijective block remap (requires gridDim.x % 8 == 0).
__device__ __forceinline__ int xcd_swz(int b, int nwg) {
  const int q = nwg >> 3;
  return (b & 7) * q + (b >> 3);
}

// ---------------------------------------------------------------------------
// Embedding: h[b,t,:] = tok_emb[x[b,t]] + pos_emb[t]  -> bf16
// ---------------------------------------------------------------------------
__global__ void embed_kernel(const int* __restrict__ x, const float* __restrict__ tok,
                             const float* __restrict__ pos, us* __restrict__ h) {
  const int total8 = BT_ * E_ / 8;
  for (int i = blockIdx.x * blockDim.x + threadIdx.x; i < total8;
       i += gridDim.x * blockDim.x) {
    const int flat = i << 3;
    const int row  = flat / E_;
    const int e    = flat - row * E_;
    const int id   = x[row];
    const float4 a0 = *reinterpret_cast<const float4*>(tok + id * E_ + e);
    const float4 a1 = *reinterpret_cast<const float4*>(tok + id * E_ + e + 4);
    const float4 p0 = *reinterpret_cast<const float4*>(pos + (row & (T_ - 1)) * E_ + e);
    const float4 p1 = *reinterpret_cast<const float4*>(pos + (row & (T_ - 1)) * E_ + e + 4);
    short8 o;
    o[0] = (short)f2bf(a0.x + p0.x); o[1] = (short)f2bf(a0.y + p0.y);
    o[2] = (short)f2bf(a0.z + p0.z); o[3] = (short)f2bf(a0.w + p0.w);
    o[4] = (short)f2bf(a1.x + p1.x); o[5] = (short)f2bf(a1.y + p1.y);
    o[6] = (short)f2bf(a1.z + p1.z); o[7] = (short)f2bf(a1.w + p1.w);
    *reinterpret_cast<short8*>(h + flat) = o;
  }
}

// ---------------------------------------------------------------------------
// Row stats: st[row] = (mean, 1/sqrt(var+eps)). One wave per row.
// ---------------------------------------------------------------------------
template<int DDOF>
__global__ void stats_kernel(const us* __restrict__ h, float2* __restrict__ st) {
  const int wave = threadIdx.x >> 6;
  const int lane = threadIdx.x & 63;
  const int row  = (blockIdx.x << 2) + wave;
  float sum = 0.f, sq = 0.f;
  if (lane < 48) {
    const short8 v = *reinterpret_cast<const short8*>(h + (size_t)row * E_ + lane * 8);
#pragma unroll
    for (int j = 0; j < 8; ++j) {
      const float f = bf2f((us)v[j]);
      sum += f; sq += f * f;
    }
  }
#pragma unroll
  for (int off = 32; off > 0; off >>= 1) {
    sum += __shfl_xor(sum, off);
    sq  += __shfl_xor(sq, off);
  }
  if (lane == 0) {
    const float mean = sum * (1.f / E_);
    const float var  = (sq - E_ * mean * mean) * (1.f / (E_ - DDOF));
    float2 o; o.x = mean; o.y = rsqrtf(var + 1e-5f);
    st[row] = o;
  }
}

// ---------------------------------------------------------------------------
// Merged weight prep: ALL transposes (+g-scale, +fp32->bf16) in one launch.
// 1D flattened grid, segment decode:
//   [0,2592)     QKV  18 x (12x12)  K=384  N=384           g=ln1g
//   [2592,3456)  proj  6 x (12x12)  K=384  N=384
//   [3456,6912)  W1    6 x (48x12)  K=384  N=1536          g=ln2g
//   [6912,10368) W2    6 x (12x48)  K=1536 N=384
//   [10368,10416)Wlm   1 x (4x12)   K=384  N=65 Ndst=128   g=lnfg
// ---------------------------------------------------------------------------
__global__ void prep_kernel(const float* __restrict__ Wq, const float* __restrict__ Wk,
                            const float* __restrict__ Wv, const float* __restrict__ Wpr,
                            const float* __restrict__ W1, const float* __restrict__ W2,
                            const float* __restrict__ Wlm,
                            us* qkvT, us* projT, us* W1T, us* W2T, us* WlmT,
                            const float* __restrict__ ln1g,
                            const float* __restrict__ ln2g,
                            const float* __restrict__ lnfg) {
  const int t = blockIdx.x;
  const float* src; us* dst; const float* g = nullptr;
  int K, N, Ndst, bx, by;
  if (t < 2592) {                         // QKV
    const int z = t / 144, rem = t % 144;
    bx = rem % 12; by = rem / 12;
    const int sel = z / 6, l = z % 6;
    src = (sel == 0 ? Wq : sel == 1 ? Wk : Wv) + (size_t)l * 147456;
    dst = qkvT + (size_t)l * 442368 + sel * 147456;
    g = ln1g + l * 384; K = 384; N = 384; Ndst = 384;
  } else if (t < 3456) {                  // proj
    const int t2 = t - 2592, l = t2 / 144, rem = t2 % 144;
    bx = rem % 12; by = rem / 12;
    src = Wpr + (size_t)l * 147456; dst = projT + (size_t)l * 147456;
    K = 384; N = 384; Ndst = 384;
  } else if (t < 6912) {                  // W1
    const int t3 = t - 3456, l = t3 / 576, rem = t3 % 576;
    bx = rem % 48; by = rem / 48;
    src = W1 + (size_t)l * 589824; dst = W1T + (size_t)l * 589824;
    g = ln2g + l * 384; K = 384; N = 1536; Ndst = 1536;
  } else if (t < 10368) {                 // W2
    const int t4 = t - 6912, l = t4 / 576, rem = t4 % 576;
    bx = rem % 12; by = rem / 12;         // by in [0,48)
    src = W2 + (size_t)l * 589824; dst = W2T + (size_t)l * 589824;
    K = 1536; N = 384; Ndst = 384;
  } else {                                // Wlm
    const int t5 = t - 10368;
    bx = t5 % 4; by = t5 / 4;
    src = Wlm; dst = WlmT; g = lnfg; K = 384; N = 65; Ndst = 128;
  }
  __shared__ float tt[32][33];
  const int n0 = bx << 5, k0 = by << 5;
  const int tx = threadIdx.x & 31, ty = threadIdx.x >> 5;
#pragma unroll
  for (int j = 0; j < 32; j += 8) {
    const int n = n0 + tx;
    tt[ty + j][tx] = (n < N) ? src[(size_t)(k0 + ty + j) * N + n] : 0.f;
  }
  __syncthreads();
  const float gk = g ? g[k0 + tx] : 1.f;
#pragma unroll
  for (int j = 0; j < 32; j += 8) {
    const int n = n0 + ty + j;
    if (n < Ndst) dst[(size_t)n * K + k0 + tx] = f2bf(tt[tx][ty + j] * gk);
  }
}

// ---------------------------------------------------------------------------
// Merged c1/c2: c1[n]=sum_k g[k]W[k][n], c2[n]=sum_k b[k]W[k][n]. K=384 all.
//   [0,108)   QKV: t = zy*6+bx, zy=(sel,l)
//   [108,252) W1:  24 blocks/layer
//   [252,254) Wlm
// ---------------------------------------------------------------------------
__global__ void c12_all(const float* __restrict__ Wq, const float* __restrict__ Wk,
                        const float* __restrict__ Wv, const float* __restrict__ W1,
                        const float* __restrict__ Wlm,
                        const float* __restrict__ ln1g, const float* __restrict__ ln1b,
                        const float* __restrict__ ln2g, const float* __restrict__ ln2b,
                        const float* __restrict__ lnfg, const float* __restrict__ lnfb,
                        float2* c12q, float2* c12f, float2* c12lm) {
  const int t = blockIdx.x;
  const float* Wz; const float* gz; const float* bz; float2* outb; int N, nb;
  if (t < 108) {
    const int bx = t % 6, zy = t / 6, sel = zy / 6, l = zy % 6;
    Wz = (sel == 0 ? Wq : sel == 1 ? Wk : Wv) + (size_t)l * 147456;
    gz = ln1g + l * 384; bz = ln1b + l * 384;
    outb = c12q + (size_t)l * 1152 + sel * 384; N = 384; nb = bx << 6;
  } else if (t < 252) {
    const int t2 = t - 108, bx = t2 % 24, l = t2 / 24;
    Wz = W1 + (size_t)l * 589824;
    gz = ln2g + l * 384; bz = ln2b + l * 384;
    outb = c12f + (size_t)l * 1536; N = 1536; nb = bx << 6;
  } else {
    const int bx = t - 252;
    Wz = Wlm; gz = lnfg; bz = lnfb;
    outb = c12lm; N = 65; nb = bx << 6;
  }
  __shared__ float p1[4][64], p2[4][64];
  const int tt = threadIdx.x;
  const int c = tt & 63, kq = tt >> 6;
  const int n = nb + c;
  float s1 = 0.f, s2 = 0.f;
  if (n < N) {
    for (int k = kq * 96; k < kq * 96 + 96; ++k) {
      const float w = Wz[(size_t)k * N + n];
      s1 = fmaf(gz[k], w, s1);
      s2 = fmaf(bz[k], w, s2);
    }
  }
  p1[kq][c] = s1; p2[kq][c] = s2;
  __syncthreads();
  if (tt < 64 && nb + tt < N) {
    float2 o;
    o.x = p1[0][tt] + p1[1][tt] + p1[2][tt] + p1[3][tt];
    o.y = p2[0][tt] + p2[1][tt] + p2[2][tt] + p2[3][tt];
    outb[nb + tt] = o;
  }
}

// ---------------------------------------------------------------------------
// Async global->LDS staging of a ROWS x (CHPR*8 us) bf16 tile. LDS dest is
// linear; XOR chunk swizzle applied on the GLOBAL source side (rule #21).
// ---------------------------------------------------------------------------
template<int ROWS, int CHPR, int NTH>
__device__ __forceinline__ void stageG(const us* g, int rowUs, us* lds, int tid) {
#pragma unroll
  for (int j = 0; j < ROWS * CHPR / NTH; ++j) {
    const int fl  = j * NTH + tid;
    const int row = fl / CHPR;
    const int c   = fl % CHPR;
    const int gc  = (CHPR == 8) ? (c ^ (row & 7)) : (c ^ ((row >> 1) & 3));
    const us* src = g + (size_t)row * rowUs + gc * 8;
    __builtin_amdgcn_global_load_lds(
        (const __attribute__((address_space(1))) u32*)src,
        (__attribute__((address_space(3))) u32*)(lds + ((fl >> 6) << 9)),
        16, 0, 0);
  }
}

// ---------------------------------------------------------------------------
// Shared K-loop machinery: tile (FM*32)x(FN*32), BK=32, 4 waves (2x2),
// BUFS-buffer / (BUFS-1)-deep prefetch, counted vmcnt, raw s_barrier.
// ---------------------------------------------------------------------------
#define GEMM_LOOP(K_, NT_)                                                        \
  const int NT = (NT_);                                                           \
  _Pragma("unroll")                                                               \
  for (int p = 0; p < BUFS - 1; ++p) {                                            \
    stageG<BM, 4, 256>(Abase + p * 32, (K_), As[p], tid);                         \
    stageG<BN, 4, 256>(Bbase + p * 32, (K_), Bs[p], tid);                         \
  }                                                                               \
  int cb = 0;                                                                     \
  for (int t = 0; t < NT; ++t) {                                                  \
    if constexpr (BUFS == 4) {                                                    \
      if (t < NT - 2)       asm volatile("s_waitcnt vmcnt(%0)" :: "n"(2 * LPS) : "memory"); \
      else if (t == NT - 2) asm volatile("s_waitcnt vmcnt(%0)" :: "n"(LPS) : "memory");     \
      else                  asm volatile("s_waitcnt vmcnt(0)" ::: "memory");      \
    } else {                                                                      \
      if (t < NT - 1)       asm volatile("s_waitcnt vmcnt(%0)" :: "n"(LPS) : "memory");     \
      else                  asm volatile("s_waitcnt vmcnt(0)" ::: "memory");      \
    }                                                                             \
    __builtin_amdgcn_s_barrier();                                                 \
    __builtin_amdgcn_sched_barrier(0);                                            \
    if (t + BUFS - 1 < NT) {                                                      \
      int ib = cb + (BUFS - 1); if (ib >= BUFS) ib -= BUFS;                       \
      stageG<BM, 4, 256>(Abase + (t + BUFS - 1) * 32, (K_), As[ib], tid);         \
      stageG<BN, 4, 256>(Bbase + (t + BUFS - 1) * 32, (K_), Bs[ib], tid);         \
    }                                                                             \
    short8 af[FM], bfr[FN];                                                       \
    _Pragma("unroll")                                                             \
    for (int mt = 0; mt < FM; ++mt) {                                             \
      const int row = wm + mt * 16 + fm;                                          \
      af[mt] = *(const short8*)(As[cb] + row * 32 + ((fg ^ ((row >> 1) & 3)) << 3)); \
    }                                                                             \
    _Pragma("unroll")                                                             \
    for (int nt = 0; nt < FN; ++nt) {                                             \
      const int row = wn + nt * 16 + fm;                                          \
      bfr[nt] = *(const short8*)(Bs[cb] + row * 32 + ((fg ^ ((row >> 1) & 3)) << 3)); \
    }                                                                             \
    _Pragma("unroll")                                                             \
    for (int mt = 0; mt < FM; ++mt)                                               \
      _Pragma("unroll")                                                           \
      for (int nt = 0; nt < FN; ++nt)                                             \
        acc[mt][nt] = __builtin_amdgcn_mfma_f32_16x16x32_bf16(af[mt], bfr[nt], acc[mt][nt], 0, 0, 0); \
    cb = (cb + 1 == BUFS) ? 0 : cb + 1;                                           \
  }

// ---------------------------------------------------------------------------
// Plain MFMA GEMM, epilogue = +bias +Res(bf16) -> bf16.  (proj, FF2)
// ---------------------------------------------------------------------------
template<int FM, int FN, int BUFS>
__global__ __launch_bounds__(256)
void gemm_mfma(const us* __restrict__ A, const us* __restrict__ Bt,
               const float* __restrict__ bias, const us* Res,
               us* __restrict__ O, int N, int K, int gx) {
  constexpr int BM = FM * 32, BN = FN * 32;
  constexpr int LPS = (BM + BN) * 4 / 256;
  __shared__ us As[BUFS][BM * 32];
  __shared__ us Bs[BUFS][BN * 32];
  const int tid = threadIdx.x;
  const int lid = xcd_swz(blockIdx.x, gridDim.x);
  const int bnI = lid % gx, bmI = lid / gx;
  const int bm = bmI * BM, bn = bnI * BN;
  const int wv = tid >> 6, ln = tid & 63;
  const int fm = ln & 15, fg = ln >> 4;
  const int wm = (wv >> 1) * (FM * 16), wn = (wv & 1) * (FN * 16);
  const us* Abase = A + (size_t)bm * K;
  const us* Bbase = Bt + (size_t)bn * K;

  f32x4 acc[FM][FN];
  const f32x4 zz = {0.f, 0.f, 0.f, 0.f};
#pragma unroll
  for (int i = 0; i < FM; ++i)
#pragma unroll
    for (int j = 0; j < FN; ++j) acc[i][j] = zz;

  GEMM_LOOP(K, K >> 5)

#pragma unroll
  for (int mt = 0; mt < FM; ++mt) {
#pragma unroll
    for (int nt = 0; nt < FN; ++nt) {
      const int col  = bn + wn + nt * 16 + fm;
      const int row0 = bm + wm + mt * 16 + fg * 4;
      const float bc = bias[col];
#pragma unroll
      for (int r = 0; r < 4; ++r) {
        const size_t idx = (size_t)(row0 + r) * N + col;
        O[idx] = f2bf(acc[mt][nt][r] + bc + bf2f(Res[idx]));
      }
    }
  }
}

// ---------------------------------------------------------------------------
// Folded-LN MFMA GEMM: A = raw h (bf16), Bt pre-scaled by g.
// out = inv*(acc - mu*c1[col]) + c2[col] (+bias).
// EPI: 0 = QKV split (q/k -> O0 [BT][768] bf16, v -> O1 [B*H][64][256] bf16)
//      2 = +bias +ReLU -> bf16 O0
//      3 = +bias, col<65 -> fp32 O0 stride 65 (LM head)
// ---------------------------------------------------------------------------
template<int FM, int FN, int EPI, int BUFS>
__global__ __launch_bounds__(256)
void gemm_fold(const us* __restrict__ A, const us* __restrict__ Bt,
               const float2* __restrict__ st, const float2* __restrict__ c12,
               const float* __restrict__ bias, void* O0, void* O1,
               int N, int gx) {
  constexpr int K = 384;
  constexpr int BM = FM * 32, BN = FN * 32;
  constexpr int LPS = (BM + BN) * 4 / 256;
  __shared__ us As[BUFS][BM * 32];
  __shared__ us Bs[BUFS][BN * 32];
  const int tid = threadIdx.x;
  const int lid = xcd_swz(blockIdx.x, gridDim.x);
  const int bnI = lid % gx, bmI = lid / gx;
  const int bm = bmI * BM, bn = bnI * BN;
  const int wv = tid >> 6, ln = tid & 63;
  const int fm = ln & 15, fg = ln >> 4;
  const int wm = (wv >> 1) * (FM * 16), wn = (wv & 1) * (FN * 16);
  const us* Abase = A + (size_t)bm * K;
  const us* Bbase = Bt + (size_t)bn * K;

  f32x4 acc[FM][FN];
  const f32x4 zz = {0.f, 0.f, 0.f, 0.f};
#pragma unroll
  for (int i = 0; i < FM; ++i)
#pragma unroll
    for (int j = 0; j < FN; ++j) acc[i][j] = zz;

  GEMM_LOOP(K, 12)

#pragma unroll
  for (int mt = 0; mt < FM; ++mt) {
    const int row0 = bm + wm + mt * 16 + fg * 4;
    float2 sr[4];
#pragma unroll
    for (int r = 0; r < 4; ++r) sr[r] = st[row0 + r];
#pragma unroll
    for (int nt = 0; nt < FN; ++nt) {
      const int col = bn + wn + nt * 16 + fm;
      if (EPI == 3 && col >= V_) continue;
      const float2 cc = c12[col];
      float vals[4];
#pragma unroll
      for (int r = 0; r < 4; ++r)
        vals[r] = sr[r].y * (acc[mt][nt][r] - sr[r].x * cc.x) + cc.y;
      if (EPI == 0) {
        if (col < 768) {
          us* qk = (us*)O0;
#pragma unroll
          for (int r = 0; r < 4; ++r)
            qk[(size_t)(row0 + r) * 768 + col] = f2bf(vals[r]);
        } else {                              // v -> transposed [B*H][64][256]
          const int d = col - 768;
          const int hh = d >> 6, dd = d & 63;
          const int bI = row0 >> 8, t0 = row0 & 255;
          us* vt = (us*)O1;
          ushort4 pk;
          pk.x = f2bf(vals[0]); pk.y = f2bf(vals[1]);
          pk.z = f2bf(vals[2]); pk.w = f2bf(vals[3]);
          *reinterpret_cast<ushort4*>(vt + ((size_t)((bI * H_ + hh) * 64 + dd)) * 256 + t0) = pk;
        }
      } else if (EPI == 2) {
        us* o = (us*)O0;
        const float bc = bias[col];
#pragma unroll
        for (int r = 0; r < 4; ++r)
          o[(size_t)(row0 + r) * N + col] = f2bf(fmaxf(vals[r] + bc, 0.f));
      } else {
        float* o = (float*)O0;
        const float bc = bias[col];
#pragma unroll
        for (int r = 0; r < 4; ++r)
          o[(size_t)(row0 + r) * V_ + col] = vals[r] + bc;
      }
    }
  }
}

// ---------------------------------------------------------------------------
// MFMA flash attention. Block = (b, h, 64-query tile); 4 waves x 16 queries.
// K/V tiles staged in LDS (double-buffered, issue-early 2-phase), CHPR=8
// XOR swizzle. qk: [BT][768] bf16; vT: [B*H][64][256] bf16; ab: [BT][384].
// ---------------------------------------------------------------------------
__global__ __launch_bounds__(256)
void attn_mfma(const us* __restrict__ qk, const us* __restrict__ vT,
               us* __restrict__ ab) {
  __shared__ us Ks[2][64 * 64];
  __shared__ us Vs[2][64 * 64];
  __shared__ us Plds[4][16 * 72];   // per-wave P tile, stride 72 (pad)
  const int tid = threadIdx.x, w = tid >> 6, l = tid & 63;
  const int m = l & 15, g = l >> 4;
  const int bi = xcd_swz(blockIdx.x, gridDim.x);
  const int b = bi / 24, rem = bi - b * 24, h = rem >> 2, qt = rem & 3;
  const int qrow = (b << 8) + (qt << 6) + (w << 4);
  const us* Kg = qk + (size_t)(b << 8) * 768 + 384 + h * 64;  // + kt*64 rows
  const us* Vg = vT + (size_t)(b * H_ + h) * 64 * 256;        // + kt*64 cols

  short8 qf0, qf1;
  {
    const us* qp = qk + (size_t)(qrow + m) * 768 + h * 64 + g * 8;
    qf0 = *(const short8*)qp;
    qf1 = *(const short8*)(qp + 32);
  }
  float mrow[4], ssum[4];
  f32x4 o[4];
  const f32x4 zz = {0.f, 0.f, 0.f, 0.f};
#pragma unroll
  for (int r = 0; r < 4; ++r) { mrow[r] = -1e30f; ssum[r] = 0.f; o[r] = zz; }

  stageG<64, 8, 256>(Kg, 768, Ks[0], tid);
  stageG<64, 8, 256>(Vg, 256, Vs[0], tid);
  __syncthreads();

  int cur = 0;
  for (int kt = 0; kt <= qt; ++kt) {
    if (kt < qt) {
      stageG<64, 8, 256>(Kg + (size_t)(kt + 1) * 64 * 768, 768, Ks[cur ^ 1], tid);
      stageG<64, 8, 256>(Vg + (kt + 1) * 64,               256, Vs[cur ^ 1], tid);
    }
    // ---- S = Q K^T (16 queries x 64 keys) from LDS ----
    f32x4 s[4];
#pragma unroll
    for (int nt = 0; nt < 4; ++nt) {
      const int row = nt * 16 + m;
      const int sw  = row & 7;
      short8 kf0 = *(const short8*)(Ks[cur] + row * 64 + ((g ^ sw) << 3));
      short8 kf1 = *(const short8*)(Ks[cur] + row * 64 + (((4 | g) ^ sw) << 3));
      f32x4 z = zz;
      z = __builtin_amdgcn_mfma_f32_16x16x32_bf16(qf0, kf0, z, 0, 0, 0);
      z = __builtin_amdgcn_mfma_f32_16x16x32_bf16(qf1, kf1, z, 0, 0, 0);
      s[nt] = z;
    }
    // ---- mask + online softmax ----
    const bool diag = (kt == qt);
    float p[4][4], tmax[4];
#pragma unroll
    for (int r = 0; r < 4; ++r) tmax[r] = -1e30f;
#pragma unroll
    for (int nt = 0; nt < 4; ++nt)
#pragma unroll
      for (int r = 0; r < 4; ++r) {
        float v = s[nt][r] * 0.125f;
        if (diag) {
          const int key = nt * 16 + m;
          const int qq  = (w << 4) + (g << 2) + r;
          if (key > qq) v = -1e30f;
        }
        p[nt][r] = v;
        tmax[r] = fmaxf(tmax[r], v);
      }
#pragma unroll
    for (int xm = 1; xm < 16; xm <<= 1)
#pragma unroll
      for (int r = 0; r < 4; ++r) tmax[r] = fmaxf(tmax[r], __shfl_xor(tmax[r], xm));
    float sc[4], tsum[4];
#pragma unroll
    for (int r = 0; r < 4; ++r) {
      const float nm = fmaxf(mrow[r], tmax[r]);
      sc[r] = __expf(mrow[r] - nm);
      mrow[r] = nm;
      tsum[r] = 0.f;
    }
#pragma unroll
    for (int nt = 0; nt < 4; ++nt)
#pragma unroll
      for (int r = 0; r < 4; ++r) {
        p[nt][r] = __expf(p[nt][r] - mrow[r]);
        tsum[r] += p[nt][r];
      }
#pragma unroll
    for (int xm = 1; xm < 16; xm <<= 1)
#pragma unroll
      for (int r = 0; r < 4; ++r) tsum[r] += __shfl_xor(tsum[r], xm);
#pragma unroll
    for (int r = 0; r < 4; ++r) ssum[r] = ssum[r] * sc[r] + tsum[r];
#pragma unroll
    for (int nt = 0; nt < 4; ++nt)
#pragma unroll
      for (int r = 0; r < 4; ++r) o[nt][r] *= sc[r];
    // ---- P -> LDS (bf16, C-layout -> A-layout transpose via LDS) ----
#pragma unroll
    for (int nt = 0; nt < 4; ++nt)
#pragma unroll
      for (int r = 0; r < 4; ++r)
        Plds[w][(g * 4 + r) * 72 + nt * 16 + m] = f2bf(p[nt][r]);
    // ---- O += P V (V from LDS) ----
#pragma unroll
    for (int kc = 0; kc < 2; ++kc) {
      short8 pa = *(const short8*)&Plds[w][m * 72 + kc * 32 + g * 8];
#pragma unroll
      for (int nd = 0; nd < 4; ++nd) {
        const int row = nd * 16 + m;
        short8 vf = *(const short8*)(Vs[cur] + row * 64 + ((((kc << 2) | g) ^ (row & 7)) << 3));
        o[nd] = __builtin_amdgcn_mfma_f32_16x16x32_bf16(pa, vf, o[nd], 0, 0, 0);
      }
    }
    __syncthreads();   // staged next tile arrived; all reads of cur done
    cur ^= 1;
  }
  // ---- normalize + write ----
#pragma unroll
  for (int r = 0; r < 4; ++r) {
    const float inv = 1.f / ssum[r];
    const size_t rowoff = (size_t)(qrow + g * 4 + r) * 384 + h * 64;
#pragma unroll
    for (int nd = 0; nd < 4; ++nd)
      ab[rowoff + nd * 16 + m] = f2bf(o[nd][r] * inv);
  }
}

// ---------------------------------------------------------------------------
extern "C" void kernel_launch(void* const* d_in, const int* in_sizes, int n_in,
                              void* d_out, int out_size, void* d_ws, size_t ws_size,
                              hipStream_t stream) {
  const int*   x    = (const int*)  d_in[0];
  const float* tok  = (const float*)d_in[1];
  const float* pos  = (const float*)d_in[2];
  const float* Wq   = (const float*)d_in[3];
  const float* Wk   = (const float*)d_in[4];
  const float* Wv   = (const float*)d_in[5];
  const float* Wpr  = (const float*)d_in[6];
  const float* bpr  = (const float*)d_in[7];
  const float* W1   = (const float*)d_in[8];
  const float* b1   = (const float*)d_in[9];
  const float* W2   = (const float*)d_in[10];
  const float* b2   = (const float*)d_in[11];
  const float* ln1g = (const float*)d_in[12];
  const float* ln1b = (const float*)d_in[13];
  const float* ln2g = (const float*)d_in[14];
  const float* ln2b = (const float*)d_in[15];
  const float* lnfg = (const float*)d_in[16];
  const float* lnfb = (const float*)d_in[17];
  const float* Wlm  = (const float*)d_in[18];
  const float* blm  = (const float*)d_in[19];
  float* out = (float*)d_out;

  char* W = (char*)d_ws;
  us*     h    = (us*)(W + 0);            // [BT][384] bf16       12.58 MB
  us*     qkb  = (us*)(W + 12582912);     // [BT][768] bf16       25.17 MB
  us*     vTb  = (us*)(W + 37748736);     // [B*H][64][256] bf16  12.58 MB
  us*     abb  = (us*)(W + 50331648);     // [BT][384] bf16       12.58 MB
  us*     ffa  = (us*)(W + 12582912);     // [BT][1536] bf16 (aliases qk+vT+ab)
  us*     qkvT = (us*)(W + 62914560);     // [L][1152][384] bf16 (g-scaled)
  us*     projT= (us*)(W + 68222976);     // [L][384][384]
  us*     W1T  = (us*)(W + 69992448);     // [L][1536][384] (g-scaled)
  us*     W2T  = (us*)(W + 77070336);     // [L][384][1536]
  us*     WlmT = (us*)(W + 84148224);     // [128][384] (g-scaled, rows 65+ zero)
  float2* st   = (float2*)(W + 84246528); // [BT] (mean, inv)     131 KB
  float2* c12q = (float2*)(W + 84377600); // [L][1152]
  float2* c12f = (float2*)(W + 84432896); // [L][1536]
  float2* c12lm= (float2*)(W + 84506624); // [65]

  // ---- merged weight prep (all transposes) + merged c1/c2 ----
  prep_kernel<<<10416, 256, 0, stream>>>(Wq, Wk, Wv, Wpr, W1, W2, Wlm,
                                         qkvT, projT, W1T, W2T, WlmT,
                                         ln1g, ln2g, lnfg);
  c12_all<<<254, 256, 0, stream>>>(Wq, Wk, Wv, W1, Wlm,
                                   ln1g, ln1b, ln2g, ln2b, lnfg, lnfb,
                                   c12q, c12f, c12lm);

  embed_kernel<<<3072, 256, 0, stream>>>(x, tok, pos, h);

  for (int l = 0; l < L_; ++l) {
    stats_kernel<1><<<BT_/4, 256, 0, stream>>>(h, st);
    // QKV (folded LN1): 128x128 tiles, BUFS=3 -> 1152 blocks  (R7 config)
    gemm_fold<4,4,0,3><<<1152, 256, 0, stream>>>(
        h, qkvT + (size_t)l*442368, st, c12q + (size_t)l*1152, nullptr,
        qkb, vTb, 1152, 9);
    attn_mfma<<<B_*H_*4, 256, 0, stream>>>(qkb, vTb, abb);
    // proj: 64x128 tiles, BUFS=4 -> 768 blocks
    gemm_mfma<2,4,4><<<768, 256, 0, stream>>>(
        abb, projT + (size_t)l*147456, bpr + l*E_, h, h, 384, 384, 3);
    stats_kernel<1><<<BT_/4, 256, 0, stream>>>(h, st);
    // FF1 (folded LN2): 128x128 tiles, BUFS=3 -> 1536 blocks  (R7 config)
    gemm_fold<4,4,2,3><<<1536, 256, 0, stream>>>(
        h, W1T + (size_t)l*589824, st, c12f + (size_t)l*1536, b1 + l*FF_,
        ffa, nullptr, 1536, 12);
    // FF2: 64x128 tiles, K=1536, BUFS=4 -> 768 blocks
    gemm_mfma<2,4,4><<<768, 256, 0, stream>>>(
        ffa, W2T + (size_t)l*589824, b2 + l*E_, h, h, 384, 1536, 3);
  }

  stats_kernel<0><<<BT_/4, 256, 0, stream>>>(h, st);
  // LM head (folded LNf): 64x128 tiles, BUFS=3 -> 256 blocks  (R7 config)
  gemm_fold<2,4,3,3><<<256, 256, 0, stream>>>(
      h, WlmT, st, c12lm, blm, out, nullptr, 128, 1);
}

// Round 16
// 915.643 us; speedup vs baseline: 1.1358x; 1.0022x over previous
//
#include <hip/hip_runtime.h>

#define L_  6
#define E_  384
#define T_  256
#define H_  6
#define D_  64
#define V_  65
#define FF_ 1536
#define B_  64
#define BT_ (B_*T_)    // 16384 rows
#define HD_ 384

typedef __attribute__((ext_vector_type(8))) short short8;
typedef __attribute__((ext_vector_type(4))) float f32x4;
typedef unsigned short us;
typedef unsigned int u32;

__device__ __forceinline__ us f2bf(float f) {
  u32 u = __float_as_uint(f);
  u32 r = (u + 0x7fffu + ((u >> 16) & 1u)) >> 16;  // RNE
  return (us)r;
}
__device__ __forceinline__ float bf2f(us v) {
  return __uint_as_float(((u32)v) << 16);
}

// XCD-chunked bijective block remap (requires gridDim.x % 8 == 0).
__device__ __forceinline__ int xcd_swz(int b, int nwg) {
  const int q = nwg >> 3;
  return (b & 7) * q + (b >> 3);
}

// ---------------------------------------------------------------------------
// Embedding: h[b,t,:] = tok_emb[x[b,t]] + pos_emb[t]  -> bf16
// ---------------------------------------------------------------------------
__global__ void embed_kernel(const int* __restrict__ x, const float* __restrict__ tok,
                             const float* __restrict__ pos, us* __restrict__ h) {
  const int total8 = BT_ * E_ / 8;
  for (int i = blockIdx.x * blockDim.x + threadIdx.x; i < total8;
       i += gridDim.x * blockDim.x) {
    const int flat = i << 3;
    const int row  = flat / E_;
    const int e    = flat - row * E_;
    const int id   = x[row];
    const float4 a0 = *reinterpret_cast<const float4*>(tok + id * E_ + e);
    const float4 a1 = *reinterpret_cast<const float4*>(tok + id * E_ + e + 4);
    const float4 p0 = *reinterpret_cast<const float4*>(pos + (row & (T_ - 1)) * E_ + e);
    const float4 p1 = *reinterpret_cast<const float4*>(pos + (row & (T_ - 1)) * E_ + e + 4);
    short8 o;
    o[0] = (short)f2bf(a0.x + p0.x); o[1] = (short)f2bf(a0.y + p0.y);
    o[2] = (short)f2bf(a0.z + p0.z); o[3] = (short)f2bf(a0.w + p0.w);
    o[4] = (short)f2bf(a1.x + p1.x); o[5] = (short)f2bf(a1.y + p1.y);
    o[6] = (short)f2bf(a1.z + p1.z); o[7] = (short)f2bf(a1.w + p1.w);
    *reinterpret_cast<short8*>(h + flat) = o;
  }
}

// ---------------------------------------------------------------------------
// Row stats: st[row] = (mean, 1/sqrt(var+eps)). One wave per row.
// ---------------------------------------------------------------------------
template<int DDOF>
__global__ void stats_kernel(const us* __restrict__ h, float2* __restrict__ st) {
  const int wave = threadIdx.x >> 6;
  const int lane = threadIdx.x & 63;
  const int row  = (blockIdx.x << 2) + wave;
  float sum = 0.f, sq = 0.f;
  if (lane < 48) {
    const short8 v = *reinterpret_cast<const short8*>(h + (size_t)row * E_ + lane * 8);
#pragma unroll
    for (int j = 0; j < 8; ++j) {
      const float f = bf2f((us)v[j]);
      sum += f; sq += f * f;
    }
  }
#pragma unroll
  for (int off = 32; off > 0; off >>= 1) {
    sum += __shfl_xor(sum, off);
    sq  += __shfl_xor(sq, off);
  }
  if (lane == 0) {
    const float mean = sum * (1.f / E_);
    const float var  = (sq - E_ * mean * mean) * (1.f / (E_ - DDOF));
    float2 o; o.x = mean; o.y = rsqrtf(var + 1e-5f);
    st[row] = o;
  }
}

// ---------------------------------------------------------------------------
// Merged weight prep: ALL transposes (+g-scale, +fp32->bf16) in one launch.
// 1D flattened grid, segment decode:
//   [0,2592)     QKV  18 x (12x12)  K=384  N=384           g=ln1g
//   [2592,3456)  proj  6 x (12x12)  K=384  N=384
//   [3456,6912)  W1    6 x (48x12)  K=384  N=1536          g=ln2g
//   [6912,10368) W2    6 x (12x48)  K=1536 N=384
//   [10368,10416)Wlm   1 x (4x12)   K=384  N=65 Ndst=128   g=lnfg
// ---------------------------------------------------------------------------
__global__ void prep_kernel(const float* __restrict__ Wq, const float* __restrict__ Wk,
                            const float* __restrict__ Wv, const float* __restrict__ Wpr,
                            const float* __restrict__ W1, const float* __restrict__ W2,
                            const float* __restrict__ Wlm,
                            us* qkvT, us* projT, us* W1T, us* W2T, us* WlmT,
                            const float* __restrict__ ln1g,
                            const float* __restrict__ ln2g,
                            const float* __restrict__ lnfg) {
  const int t = blockIdx.x;
  const float* src; us* dst; const float* g = nullptr;
  int K, N, Ndst, bx, by;
  if (t < 2592) {                         // QKV
    const int z = t / 144, rem = t % 144;
    bx = rem % 12; by = rem / 12;
    const int sel = z / 6, l = z % 6;
    src = (sel == 0 ? Wq : sel == 1 ? Wk : Wv) + (size_t)l * 147456;
    dst = qkvT + (size_t)l * 442368 + sel * 147456;
    g = ln1g + l * 384; K = 384; N = 384; Ndst = 384;
  } else if (t < 3456) {                  // proj
    const int t2 = t - 2592, l = t2 / 144, rem = t2 % 144;
    bx = rem % 12; by = rem / 12;
    src = Wpr + (size_t)l * 147456; dst = projT + (size_t)l * 147456;
    K = 384; N = 384; Ndst = 384;
  } else if (t < 6912) {                  // W1
    const int t3 = t - 3456, l = t3 / 576, rem = t3 % 576;
    bx = rem % 48; by = rem / 48;
    src = W1 + (size_t)l * 589824; dst = W1T + (size_t)l * 589824;
    g = ln2g + l * 384; K = 384; N = 1536; Ndst = 1536;
  } else if (t < 10368) {                 // W2
    const int t4 = t - 6912, l = t4 / 576, rem = t4 % 576;
    bx = rem % 12; by = rem / 12;         // by in [0,48)
    src = W2 + (size_t)l * 589824; dst = W2T + (size_t)l * 589824;
    K = 1536; N = 384; Ndst = 384;
  } else {                                // Wlm
    const int t5 = t - 10368;
    bx = t5 % 4; by = t5 / 4;
    src = Wlm; dst = WlmT; g = lnfg; K = 384; N = 65; Ndst = 128;
  }
  __shared__ float tt[32][33];
  const int n0 = bx << 5, k0 = by << 5;
  const int tx = threadIdx.x & 31, ty = threadIdx.x >> 5;
#pragma unroll
  for (int j = 0; j < 32; j += 8) {
    const int n = n0 + tx;
    tt[ty + j][tx] = (n < N) ? src[(size_t)(k0 + ty + j) * N + n] : 0.f;
  }
  __syncthreads();
  const float gk = g ? g[k0 + tx] : 1.f;
#pragma unroll
  for (int j = 0; j < 32; j += 8) {
    const int n = n0 + ty + j;
    if (n < Ndst) dst[(size_t)n * K + k0 + tx] = f2bf(tt[tx][ty + j] * gk);
  }
}

// ---------------------------------------------------------------------------
// Merged c1/c2: c1[n]=sum_k g[k]W[k][n], c2[n]=sum_k b[k]W[k][n]. K=384 all.
//   [0,108)   QKV: t = zy*6+bx, zy=(sel,l)
//   [108,252) W1:  24 blocks/layer
//   [252,254) Wlm
// ---------------------------------------------------------------------------
__global__ void c12_all(const float* __restrict__ Wq, const float* __restrict__ Wk,
                        const float* __restrict__ Wv, const float* __restrict__ W1,
                        const float* __restrict__ Wlm,
                        const float* __restrict__ ln1g, const float* __restrict__ ln1b,
                        const float* __restrict__ ln2g, const float* __restrict__ ln2b,
                        const float* __restrict__ lnfg, const float* __restrict__ lnfb,
                        float2* c12q, float2* c12f, float2* c12lm) {
  const int t = blockIdx.x;
  const float* Wz; const float* gz; const float* bz; float2* outb; int N, nb;
  if (t < 108) {
    const int bx = t % 6, zy = t / 6, sel = zy / 6, l = zy % 6;
    Wz = (sel == 0 ? Wq : sel == 1 ? Wk : Wv) + (size_t)l * 147456;
    gz = ln1g + l * 384; bz = ln1b + l * 384;
    outb = c12q + (size_t)l * 1152 + sel * 384; N = 384; nb = bx << 6;
  } else if (t < 252) {
    const int t2 = t - 108, bx = t2 % 24, l = t2 / 24;
    Wz = W1 + (size_t)l * 589824;
    gz = ln2g + l * 384; bz = ln2b + l * 384;
    outb = c12f + (size_t)l * 1536; N = 1536; nb = bx << 6;
  } else {
    const int bx = t - 252;
    Wz = Wlm; gz = lnfg; bz = lnfb;
    outb = c12lm; N = 65; nb = bx << 6;
  }
  __shared__ float p1[4][64], p2[4][64];
  const int tt = threadIdx.x;
  const int c = tt & 63, kq = tt >> 6;
  const int n = nb + c;
  float s1 = 0.f, s2 = 0.f;
  if (n < N) {
    for (int k = kq * 96; k < kq * 96 + 96; ++k) {
      const float w = Wz[(size_t)k * N + n];
      s1 = fmaf(gz[k], w, s1);
      s2 = fmaf(bz[k], w, s2);
    }
  }
  p1[kq][c] = s1; p2[kq][c] = s2;
  __syncthreads();
  if (tt < 64 && nb + tt < N) {
    float2 o;
    o.x = p1[0][tt] + p1[1][tt] + p1[2][tt] + p1[3][tt];
    o.y = p2[0][tt] + p2[1][tt] + p2[2][tt] + p2[3][tt];
    outb[nb + tt] = o;
  }
}

// ---------------------------------------------------------------------------
// Async global->LDS staging of a ROWS x (CHPR*8 us) bf16 tile. LDS dest is
// linear; XOR chunk swizzle applied on the GLOBAL source side (rule #21).
// ---------------------------------------------------------------------------
template<int ROWS, int CHPR, int NTH>
__device__ __forceinline__ void stageG(const us* g, int rowUs, us* lds, int tid) {
#pragma unroll
  for (int j = 0; j < ROWS * CHPR / NTH; ++j) {
    const int fl  = j * NTH + tid;
    const int row = fl / CHPR;
    const int c   = fl % CHPR;
    const int gc  = (CHPR == 8) ? (c ^ (row & 7)) : (c ^ ((row >> 1) & 3));
    const us* src = g + (size_t)row * rowUs + gc * 8;
    __builtin_amdgcn_global_load_lds(
        (const __attribute__((address_space(1))) u32*)src,
        (__attribute__((address_space(3))) u32*)(lds + ((fl >> 6) << 9)),
        16, 0, 0);
  }
}

// ---------------------------------------------------------------------------
// Shared K-loop machinery: tile (FM*32)x(FN*32), BK=32, 4 waves (2x2),
// BUFS-buffer / (BUFS-1)-deep prefetch, counted vmcnt, raw s_barrier.
// T5: s_setprio(1) around the MFMA cluster (counted-vmcnt phase-split
// structure -> scheduler can favor MFMA-entering waves; m218b).
// ---------------------------------------------------------------------------
#define GEMM_LOOP(K_, NT_)                                                        \
  const int NT = (NT_);                                                           \
  _Pragma("unroll")                                                               \
  for (int p = 0; p < BUFS - 1; ++p) {                                            \
    stageG<BM, 4, 256>(Abase + p * 32, (K_), As[p], tid);                         \
    stageG<BN, 4, 256>(Bbase + p * 32, (K_), Bs[p], tid);                         \
  }                                                                               \
  int cb = 0;                                                                     \
  for (int t = 0; t < NT; ++t) {                                                  \
    if constexpr (BUFS == 4) {                                                    \
      if (t < NT - 2)       asm volatile("s_waitcnt vmcnt(%0)" :: "n"(2 * LPS) : "memory"); \
      else if (t == NT - 2) asm volatile("s_waitcnt vmcnt(%0)" :: "n"(LPS) : "memory");     \
      else                  asm volatile("s_waitcnt vmcnt(0)" ::: "memory");      \
    } else {                                                                      \
      if (t < NT - 1)       asm volatile("s_waitcnt vmcnt(%0)" :: "n"(LPS) : "memory");     \
      else                  asm volatile("s_waitcnt vmcnt(0)" ::: "memory");      \
    }                                                                             \
    __builtin_amdgcn_s_barrier();                                                 \
    __builtin_amdgcn_sched_barrier(0);                                            \
    if (t + BUFS - 1 < NT) {                                                      \
      int ib = cb + (BUFS - 1); if (ib >= BUFS) ib -= BUFS;                       \
      stageG<BM, 4, 256>(Abase + (t + BUFS - 1) * 32, (K_), As[ib], tid);         \
      stageG<BN, 4, 256>(Bbase + (t + BUFS - 1) * 32, (K_), Bs[ib], tid);         \
    }                                                                             \
    short8 af[FM], bfr[FN];                                                       \
    _Pragma("unroll")                                                             \
    for (int mt = 0; mt < FM; ++mt) {                                             \
      const int row = wm + mt * 16 + fm;                                          \
      af[mt] = *(const short8*)(As[cb] + row * 32 + ((fg ^ ((row >> 1) & 3)) << 3)); \
    }                                                                             \
    _Pragma("unroll")                                                             \
    for (int nt = 0; nt < FN; ++nt) {                                             \
      const int row = wn + nt * 16 + fm;                                          \
      bfr[nt] = *(const short8*)(Bs[cb] + row * 32 + ((fg ^ ((row >> 1) & 3)) << 3)); \
    }                                                                             \
    __builtin_amdgcn_s_setprio(1);                                                \
    _Pragma("unroll")                                                             \
    for (int mt = 0; mt < FM; ++mt)                                               \
      _Pragma("unroll")                                                           \
      for (int nt = 0; nt < FN; ++nt)                                             \
        acc[mt][nt] = __builtin_amdgcn_mfma_f32_16x16x32_bf16(af[mt], bfr[nt], acc[mt][nt], 0, 0, 0); \
    __builtin_amdgcn_s_setprio(0);                                                \
    cb = (cb + 1 == BUFS) ? 0 : cb + 1;                                           \
  }

// ---------------------------------------------------------------------------
// Plain MFMA GEMM, epilogue = +bias +Res(bf16) -> bf16.  (proj, FF2)
// ---------------------------------------------------------------------------
template<int FM, int FN, int BUFS>
__global__ __launch_bounds__(256)
void gemm_mfma(const us* __restrict__ A, const us* __restrict__ Bt,
               const float* __restrict__ bias, const us* Res,
               us* __restrict__ O, int N, int K, int gx) {
  constexpr int BM = FM * 32, BN = FN * 32;
  constexpr int LPS = (BM + BN) * 4 / 256;
  __shared__ us As[BUFS][BM * 32];
  __shared__ us Bs[BUFS][BN * 32];
  const int tid = threadIdx.x;
  const int lid = xcd_swz(blockIdx.x, gridDim.x);
  const int bnI = lid % gx, bmI = lid / gx;
  const int bm = bmI * BM, bn = bnI * BN;
  const int wv = tid >> 6, ln = tid & 63;
  const int fm = ln & 15, fg = ln >> 4;
  const int wm = (wv >> 1) * (FM * 16), wn = (wv & 1) * (FN * 16);
  const us* Abase = A + (size_t)bm * K;
  const us* Bbase = Bt + (size_t)bn * K;

  f32x4 acc[FM][FN];
  const f32x4 zz = {0.f, 0.f, 0.f, 0.f};
#pragma unroll
  for (int i = 0; i < FM; ++i)
#pragma unroll
    for (int j = 0; j < FN; ++j) acc[i][j] = zz;

  GEMM_LOOP(K, K >> 5)

#pragma unroll
  for (int mt = 0; mt < FM; ++mt) {
#pragma unroll
    for (int nt = 0; nt < FN; ++nt) {
      const int col  = bn + wn + nt * 16 + fm;
      const int row0 = bm + wm + mt * 16 + fg * 4;
      const float bc = bias[col];
#pragma unroll
      for (int r = 0; r < 4; ++r) {
        const size_t idx = (size_t)(row0 + r) * N + col;
        O[idx] = f2bf(acc[mt][nt][r] + bc + bf2f(Res[idx]));
      }
    }
  }
}

// ---------------------------------------------------------------------------
// Folded-LN MFMA GEMM: A = raw h (bf16), Bt pre-scaled by g.
// out = inv*(acc - mu*c1[col]) + c2[col] (+bias).
// EPI: 0 = QKV split (q/k -> O0 [BT][768] bf16, v -> O1 [B*H][64][256] bf16)
//      2 = +bias +ReLU -> bf16 O0
//      3 = +bias, col<65 -> fp32 O0 stride 65 (LM head)
// ---------------------------------------------------------------------------
template<int FM, int FN, int EPI, int BUFS>
__global__ __launch_bounds__(256)
void gemm_fold(const us* __restrict__ A, const us* __restrict__ Bt,
               const float2* __restrict__ st, const float2* __restrict__ c12,
               const float* __restrict__ bias, void* O0, void* O1,
               int N, int gx) {
  constexpr int K = 384;
  constexpr int BM = FM * 32, BN = FN * 32;
  constexpr int LPS = (BM + BN) * 4 / 256;
  __shared__ us As[BUFS][BM * 32];
  __shared__ us Bs[BUFS][BN * 32];
  const int tid = threadIdx.x;
  const int lid = xcd_swz(blockIdx.x, gridDim.x);
  const int bnI = lid % gx, bmI = lid / gx;
  const int bm = bmI * BM, bn = bnI * BN;
  const int wv = tid >> 6, ln = tid & 63;
  const int fm = ln & 15, fg = ln >> 4;
  const int wm = (wv >> 1) * (FM * 16), wn = (wv & 1) * (FN * 16);
  const us* Abase = A + (size_t)bm * K;
  const us* Bbase = Bt + (size_t)bn * K;

  f32x4 acc[FM][FN];
  const f32x4 zz = {0.f, 0.f, 0.f, 0.f};
#pragma unroll
  for (int i = 0; i < FM; ++i)
#pragma unroll
    for (int j = 0; j < FN; ++j) acc[i][j] = zz;

  GEMM_LOOP(K, 12)

#pragma unroll
  for (int mt = 0; mt < FM; ++mt) {
    const int row0 = bm + wm + mt * 16 + fg * 4;
    float2 sr[4];
#pragma unroll
    for (int r = 0; r < 4; ++r) sr[r] = st[row0 + r];
#pragma unroll
    for (int nt = 0; nt < FN; ++nt) {
      const int col = bn + wn + nt * 16 + fm;
      if (EPI == 3 && col >= V_) continue;
      const float2 cc = c12[col];
      float vals[4];
#pragma unroll
      for (int r = 0; r < 4; ++r)
        vals[r] = sr[r].y * (acc[mt][nt][r] - sr[r].x * cc.x) + cc.y;
      if (EPI == 0) {
        if (col < 768) {
          us* qk = (us*)O0;
#pragma unroll
          for (int r = 0; r < 4; ++r)
            qk[(size_t)(row0 + r) * 768 + col] = f2bf(vals[r]);
        } else {                              // v -> transposed [B*H][64][256]
          const int d = col - 768;
          const int hh = d >> 6, dd = d & 63;
          const int bI = row0 >> 8, t0 = row0 & 255;
          us* vt = (us*)O1;
          ushort4 pk;
          pk.x = f2bf(vals[0]); pk.y = f2bf(vals[1]);
          pk.z = f2bf(vals[2]); pk.w = f2bf(vals[3]);
          *reinterpret_cast<ushort4*>(vt + ((size_t)((bI * H_ + hh) * 64 + dd)) * 256 + t0) = pk;
        }
      } else if (EPI == 2) {
        us* o = (us*)O0;
        const float bc = bias[col];
#pragma unroll
        for (int r = 0; r < 4; ++r)
          o[(size_t)(row0 + r) * N + col] = f2bf(fmaxf(vals[r] + bc, 0.f));
      } else {
        float* o = (float*)O0;
        const float bc = bias[col];
#pragma unroll
        for (int r = 0; r < 4; ++r)
          o[(size_t)(row0 + r) * V_ + col] = vals[r] + bc;
      }
    }
  }
}

// ---------------------------------------------------------------------------
// MFMA flash attention. Block = (b, h, 64-query tile); 4 waves x 16 queries.
// K/V tiles staged in LDS (double-buffered, issue-early 2-phase), CHPR=8
// XOR swizzle. qk: [BT][768] bf16; vT: [B*H][64][256] bf16; ab: [BT][384].
// ---------------------------------------------------------------------------
__global__ __launch_bounds__(256)
void attn_mfma(const us* __restrict__ qk, const us* __restrict__ vT,
               us* __restrict__ ab) {
  __shared__ us Ks[2][64 * 64];
  __shared__ us Vs[2][64 * 64];
  __shared__ us Plds[4][16 * 72];   // per-wave P tile, stride 72 (pad)
  const int tid = threadIdx.x, w = tid >> 6, l = tid & 63;
  const int m = l & 15, g = l >> 4;
  const int bi = xcd_swz(blockIdx.x, gridDim.x);
  const int b = bi / 24, rem = bi - b * 24, h = rem >> 2, qt = rem & 3;
  const int qrow = (b << 8) + (qt << 6) + (w << 4);
  const us* Kg = qk + (size_t)(b << 8) * 768 + 384 + h * 64;  // + kt*64 rows
  const us* Vg = vT + (size_t)(b * H_ + h) * 64 * 256;        // + kt*64 cols

  short8 qf0, qf1;
  {
    const us* qp = qk + (size_t)(qrow + m) * 768 + h * 64 + g * 8;
    qf0 = *(const short8*)qp;
    qf1 = *(const short8*)(qp + 32);
  }
  float mrow[4], ssum[4];
  f32x4 o[4];
  const f32x4 zz = {0.f, 0.f, 0.f, 0.f};
#pragma unroll
  for (int r = 0; r < 4; ++r) { mrow[r] = -1e30f; ssum[r] = 0.f; o[r] = zz; }

  stageG<64, 8, 256>(Kg, 768, Ks[0], tid);
  stageG<64, 8, 256>(Vg, 256, Vs[0], tid);
  __syncthreads();

  int cur = 0;
  for (int kt = 0; kt <= qt; ++kt) {
    if (kt < qt) {
      stageG<64, 8, 256>(Kg + (size_t)(kt + 1) * 64 * 768, 768, Ks[cur ^ 1], tid);
      stageG<64, 8, 256>(Vg + (kt + 1) * 64,               256, Vs[cur ^ 1], tid);
    }
    // ---- S = Q K^T (16 queries x 64 keys) from LDS ----
    f32x4 s[4];
    __builtin_amdgcn_s_setprio(1);
#pragma unroll
    for (int nt = 0; nt < 4; ++nt) {
      const int row = nt * 16 + m;
      const int sw  = row & 7;
      short8 kf0 = *(const short8*)(Ks[cur] + row * 64 + ((g ^ sw) << 3));
      short8 kf1 = *(const short8*)(Ks[cur] + row * 64 + (((4 | g) ^ sw) << 3));
      f32x4 z = zz;
      z = __builtin_amdgcn_mfma_f32_16x16x32_bf16(qf0, kf0, z, 0, 0, 0);
      z = __builtin_amdgcn_mfma_f32_16x16x32_bf16(qf1, kf1, z, 0, 0, 0);
      s[nt] = z;
    }
    __builtin_amdgcn_s_setprio(0);
    // ---- mask + online softmax ----
    const bool diag = (kt == qt);
    float p[4][4], tmax[4];
#pragma unroll
    for (int r = 0; r < 4; ++r) tmax[r] = -1e30f;
#pragma unroll
    for (int nt = 0; nt < 4; ++nt)
#pragma unroll
      for (int r = 0; r < 4; ++r) {
        float v = s[nt][r] * 0.125f;
        if (diag) {
          const int key = nt * 16 + m;
          const int qq  = (w << 4) + (g << 2) + r;
          if (key > qq) v = -1e30f;
        }
        p[nt][r] = v;
        tmax[r] = fmaxf(tmax[r], v);
      }
#pragma unroll
    for (int xm = 1; xm < 16; xm <<= 1)
#pragma unroll
      for (int r = 0; r < 4; ++r) tmax[r] = fmaxf(tmax[r], __shfl_xor(tmax[r], xm));
    float sc[4], tsum[4];
#pragma unroll
    for (int r = 0; r < 4; ++r) {
      const float nm = fmaxf(mrow[r], tmax[r]);
      sc[r] = __expf(mrow[r] - nm);
      mrow[r] = nm;
      tsum[r] = 0.f;
    }
#pragma unroll
    for (int nt = 0; nt < 4; ++nt)
#pragma unroll
      for (int r = 0; r < 4; ++r) {
        p[nt][r] = __expf(p[nt][r] - mrow[r]);
        tsum[r] += p[nt][r];
      }
#pragma unroll
    for (int xm = 1; xm < 16; xm <<= 1)
#pragma unroll
      for (int r = 0; r < 4; ++r) tsum[r] += __shfl_xor(tsum[r], xm);
#pragma unroll
    for (int r = 0; r < 4; ++r) ssum[r] = ssum[r] * sc[r] + tsum[r];
#pragma unroll
    for (int nt = 0; nt < 4; ++nt)
#pragma unroll
      for (int r = 0; r < 4; ++r) o[nt][r] *= sc[r];
    // ---- P -> LDS (bf16, C-layout -> A-layout transpose via LDS) ----
#pragma unroll
    for (int nt = 0; nt < 4; ++nt)
#pragma unroll
      for (int r = 0; r < 4; ++r)
        Plds[w][(g * 4 + r) * 72 + nt * 16 + m] = f2bf(p[nt][r]);
    // ---- O += P V (V from LDS) ----
    __builtin_amdgcn_s_setprio(1);
#pragma unroll
    for (int kc = 0; kc < 2; ++kc) {
      short8 pa = *(const short8*)&Plds[w][m * 72 + kc * 32 + g * 8];
#pragma unroll
      for (int nd = 0; nd < 4; ++nd) {
        const int row = nd * 16 + m;
        short8 vf = *(const short8*)(Vs[cur] + row * 64 + ((((kc << 2) | g) ^ (row & 7)) << 3));
        o[nd] = __builtin_amdgcn_mfma_f32_16x16x32_bf16(pa, vf, o[nd], 0, 0, 0);
      }
    }
    __builtin_amdgcn_s_setprio(0);
    __syncthreads();   // staged next tile arrived; all reads of cur done
    cur ^= 1;
  }
  // ---- normalize + write ----
#pragma unroll
  for (int r = 0; r < 4; ++r) {
    const float inv = 1.f / ssum[r];
    const size_t rowoff = (size_t)(qrow + g * 4 + r) * 384 + h * 64;
#pragma unroll
    for (int nd = 0; nd < 4; ++nd)
      ab[rowoff + nd * 16 + m] = f2bf(o[nd][r] * inv);
  }
}

// ---------------------------------------------------------------------------
extern "C" void kernel_launch(void* const* d_in, const int* in_sizes, int n_in,
                              void* d_out, int out_size, void* d_ws, size_t ws_size,
                              hipStream_t stream) {
  const int*   x    = (const int*)  d_in[0];
  const float* tok  = (const float*)d_in[1];
  const float* pos  = (const float*)d_in[2];
  const float* Wq   = (const float*)d_in[3];
  const float* Wk   = (const float*)d_in[4];
  const float* Wv   = (const float*)d_in[5];
  const float* Wpr  = (const float*)d_in[6];
  const float* bpr  = (const float*)d_in[7];
  const float* W1   = (const float*)d_in[8];
  const float* b1   = (const float*)d_in[9];
  const float* W2   = (const float*)d_in[10];
  const float* b2   = (const float*)d_in[11];
  const float* ln1g = (const float*)d_in[12];
  const float* ln1b = (const float*)d_in[13];
  const float* ln2g = (const float*)d_in[14];
  const float* ln2b = (const float*)d_in[15];
  const float* lnfg = (const float*)d_in[16];
  const float* lnfb = (const float*)d_in[17];
  const float* Wlm  = (const float*)d_in[18];
  const float* blm  = (const float*)d_in[19];
  float* out = (float*)d_out;

  char* W = (char*)d_ws;
  us*     h    = (us*)(W + 0);            // [BT][384] bf16       12.58 MB
  us*     qkb  = (us*)(W + 12582912);     // [BT][768] bf16       25.17 MB
  us*     vTb  = (us*)(W + 37748736);     // [B*H][64][256] bf16  12.58 MB
  us*     abb  = (us*)(W + 50331648);     // [BT][384] bf16       12.58 MB
  us*     ffa  = (us*)(W + 12582912);     // [BT][1536] bf16 (aliases qk+vT+ab)
  us*     qkvT = (us*)(W + 62914560);     // [L][1152][384] bf16 (g-scaled)
  us*     projT= (us*)(W + 68222976);     // [L][384][384]
  us*     W1T  = (us*)(W + 69992448);     // [L][1536][384] (g-scaled)
  us*     W2T  = (us*)(W + 77070336);     // [L][384][1536]
  us*     WlmT = (us*)(W + 84148224);     // [128][384] (g-scaled, rows 65+ zero)
  float2* st   = (float2*)(W + 84246528); // [BT] (mean, inv)     131 KB
  float2* c12q = (float2*)(W + 84377600); // [L][1152]
  float2* c12f = (float2*)(W + 84432896); // [L][1536]
  float2* c12lm= (float2*)(W + 84506624); // [65]

  // ---- merged weight prep (all transposes) + merged c1/c2 ----
  prep_kernel<<<10416, 256, 0, stream>>>(Wq, Wk, Wv, Wpr, W1, W2, Wlm,
                                         qkvT, projT, W1T, W2T, WlmT,
                                         ln1g, ln2g, lnfg);
  c12_all<<<254, 256, 0, stream>>>(Wq, Wk, Wv, W1, Wlm,
                                   ln1g, ln1b, ln2g, ln2b, lnfg, lnfb,
                                   c12q, c12f, c12lm);

  embed_kernel<<<3072, 256, 0, stream>>>(x, tok, pos, h);

  for (int l = 0; l < L_; ++l) {
    stats_kernel<1><<<BT_/4, 256, 0, stream>>>(h, st);
    // QKV (folded LN1): 128x128 tiles, BUFS=3 -> 1152 blocks
    gemm_fold<4,4,0,3><<<1152, 256, 0, stream>>>(
        h, qkvT + (size_t)l*442368, st, c12q + (size_t)l*1152, nullptr,
        qkb, vTb, 1152, 9);
    attn_mfma<<<B_*H_*4, 256, 0, stream>>>(qkb, vTb, abb);
    // proj: 64x128 tiles, BUFS=4 -> 768 blocks
    gemm_mfma<2,4,4><<<768, 256, 0, stream>>>(
        abb, projT + (size_t)l*147456, bpr + l*E_, h, h, 384, 384, 3);
    stats_kernel<1><<<BT_/4, 256, 0, stream>>>(h, st);
    // FF1 (folded LN2): 128x128 tiles, BUFS=3 -> 1536 blocks
    gemm_fold<4,4,2,3><<<1536, 256, 0, stream>>>(
        h, W1T + (size_t)l*589824, st, c12f + (size_t)l*1536, b1 + l*FF_,
        ffa, nullptr, 1536, 12);
    // FF2: 64x128 tiles, K=1536, BUFS=4 -> 768 blocks
    gemm_mfma<2,4,4><<<768, 256, 0, stream>>>(
        ffa, W2T + (size_t)l*589824, b2 + l*E_, h, h, 384, 1536, 3);
  }

  stats_kernel<0><<<BT_/4, 256, 0, stream>>>(h, st);
  // LM head (folded LNf): 64x128 tiles, BUFS=3 -> 256 blocks
  gemm_fold<2,4,3,3><<<256, 256, 0, stream>>>(
      h, WlmT, st, c12lm, blm, out, nullptr, 128, 1);
}

// Round 17
// 875.551 us; speedup vs baseline: 1.1878x; 1.0458x over previous
//
#include <hip/hip_runtime.h>

#define L_  6
#define E_  384
#define T_  256
#define H_  6
#define D_  64
#define V_  65
#define FF_ 1536
#define B_  64
#define BT_ (B_*T_)    // 16384 rows
#define HD_ 384

typedef __attribute__((ext_vector_type(8))) short short8;
typedef __attribute__((ext_vector_type(4))) float f32x4;
typedef unsigned short us;
typedef unsigned int u32;

__device__ __forceinline__ us f2bf(float f) {
  u32 u = __float_as_uint(f);
  u32 r = (u + 0x7fffu + ((u >> 16) & 1u)) >> 16;  // RNE
  return (us)r;
}
__device__ __forceinline__ float bf2f(us v) {
  return __uint_as_float(((u32)v) << 16);
}

// XCD-chunked bijective block remap (requires gridDim.x % 8 == 0).
__device__ __forceinline__ int xcd_swz(int b, int nwg) {
  const int q = nwg >> 3;
  return (b & 7) * q + (b >> 3);
}

// ---------------------------------------------------------------------------
// Embedding: h[b,t,:] = tok_emb[x[b,t]] + pos_emb[t]  -> bf16
// ---------------------------------------------------------------------------
__global__ void embed_kernel(const int* __restrict__ x, const float* __restrict__ tok,
                             const float* __restrict__ pos, us* __restrict__ h) {
  const int total8 = BT_ * E_ / 8;
  for (int i = blockIdx.x * blockDim.x + threadIdx.x; i < total8;
       i += gridDim.x * blockDim.x) {
    const int flat = i << 3;
    const int row  = flat / E_;
    const int e    = flat - row * E_;
    const int id   = x[row];
    const float4 a0 = *reinterpret_cast<const float4*>(tok + id * E_ + e);
    const float4 a1 = *reinterpret_cast<const float4*>(tok + id * E_ + e + 4);
    const float4 p0 = *reinterpret_cast<const float4*>(pos + (row & (T_ - 1)) * E_ + e);
    const float4 p1 = *reinterpret_cast<const float4*>(pos + (row & (T_ - 1)) * E_ + e + 4);
    short8 o;
    o[0] = (short)f2bf(a0.x + p0.x); o[1] = (short)f2bf(a0.y + p0.y);
    o[2] = (short)f2bf(a0.z + p0.z); o[3] = (short)f2bf(a0.w + p0.w);
    o[4] = (short)f2bf(a1.x + p1.x); o[5] = (short)f2bf(a1.y + p1.y);
    o[6] = (short)f2bf(a1.z + p1.z); o[7] = (short)f2bf(a1.w + p1.w);
    *reinterpret_cast<short8*>(h + flat) = o;
  }
}

// ---------------------------------------------------------------------------
// Row stats: st[row] = (mean, 1/sqrt(var+eps)). One wave per row, 8 waves/blk.
// ---------------------------------------------------------------------------
template<int DDOF>
__global__ __launch_bounds__(512)
void stats_kernel(const us* __restrict__ h, float2* __restrict__ st) {
  const int wave = threadIdx.x >> 6;
  const int lane = threadIdx.x & 63;
  const int row  = (blockIdx.x << 3) + wave;
  float sum = 0.f, sq = 0.f;
  if (lane < 48) {
    const short8 v = *reinterpret_cast<const short8*>(h + (size_t)row * E_ + lane * 8);
#pragma unroll
    for (int j = 0; j < 8; ++j) {
      const float f = bf2f((us)v[j]);
      sum += f; sq += f * f;
    }
  }
#pragma unroll
  for (int off = 32; off > 0; off >>= 1) {
    sum += __shfl_xor(sum, off);
    sq  += __shfl_xor(sq, off);
  }
  if (lane == 0) {
    const float mean = sum * (1.f / E_);
    const float var  = (sq - E_ * mean * mean) * (1.f / (E_ - DDOF));
    float2 o; o.x = mean; o.y = rsqrtf(var + 1e-5f);
    st[row] = o;
  }
}

// ---------------------------------------------------------------------------
// Merged weight prep: ALL transposes (+g-scale, +fp32->bf16) in one launch.
// ---------------------------------------------------------------------------
__global__ void prep_kernel(const float* __restrict__ Wq, const float* __restrict__ Wk,
                            const float* __restrict__ Wv, const float* __restrict__ Wpr,
                            const float* __restrict__ W1, const float* __restrict__ W2,
                            const float* __restrict__ Wlm,
                            us* qkvT, us* projT, us* W1T, us* W2T, us* WlmT,
                            const float* __restrict__ ln1g,
                            const float* __restrict__ ln2g,
                            const float* __restrict__ lnfg) {
  const int t = blockIdx.x;
  const float* src; us* dst; const float* g = nullptr;
  int K, N, Ndst, bx, by;
  if (t < 2592) {                         // QKV
    const int z = t / 144, rem = t % 144;
    bx = rem % 12; by = rem / 12;
    const int sel = z / 6, l = z % 6;
    src = (sel == 0 ? Wq : sel == 1 ? Wk : Wv) + (size_t)l * 147456;
    dst = qkvT + (size_t)l * 442368 + sel * 147456;
    g = ln1g + l * 384; K = 384; N = 384; Ndst = 384;
  } else if (t < 3456) {                  // proj
    const int t2 = t - 2592, l = t2 / 144, rem = t2 % 144;
    bx = rem % 12; by = rem / 12;
    src = Wpr + (size_t)l * 147456; dst = projT + (size_t)l * 147456;
    K = 384; N = 384; Ndst = 384;
  } else if (t < 6912) {                  // W1
    const int t3 = t - 3456, l = t3 / 576, rem = t3 % 576;
    bx = rem % 48; by = rem / 48;
    src = W1 + (size_t)l * 589824; dst = W1T + (size_t)l * 589824;
    g = ln2g + l * 384; K = 384; N = 1536; Ndst = 1536;
  } else if (t < 10368) {                 // W2
    const int t4 = t - 6912, l = t4 / 576, rem = t4 % 576;
    bx = rem % 12; by = rem / 12;
    src = W2 + (size_t)l * 589824; dst = W2T + (size_t)l * 589824;
    K = 1536; N = 384; Ndst = 384;
  } else {                                // Wlm
    const int t5 = t - 10368;
    bx = t5 % 4; by = t5 / 4;
    src = Wlm; dst = WlmT; g = lnfg; K = 384; N = 65; Ndst = 128;
  }
  __shared__ float tt[32][33];
  const int n0 = bx << 5, k0 = by << 5;
  const int tx = threadIdx.x & 31, ty = threadIdx.x >> 5;
#pragma unroll
  for (int j = 0; j < 32; j += 8) {
    const int n = n0 + tx;
    tt[ty + j][tx] = (n < N) ? src[(size_t)(k0 + ty + j) * N + n] : 0.f;
  }
  __syncthreads();
  const float gk = g ? g[k0 + tx] : 1.f;
#pragma unroll
  for (int j = 0; j < 32; j += 8) {
    const int n = n0 + ty + j;
    if (n < Ndst) dst[(size_t)n * K + k0 + tx] = f2bf(tt[tx][ty + j] * gk);
  }
}

// ---------------------------------------------------------------------------
// Merged c1/c2: c1[n]=sum_k g[k]W[k][n], c2[n]=sum_k b[k]W[k][n]. K=384 all.
// ---------------------------------------------------------------------------
__global__ void c12_all(const float* __restrict__ Wq, const float* __restrict__ Wk,
                        const float* __restrict__ Wv, const float* __restrict__ W1,
                        const float* __restrict__ Wlm,
                        const float* __restrict__ ln1g, const float* __restrict__ ln1b,
                        const float* __restrict__ ln2g, const float* __restrict__ ln2b,
                        const float* __restrict__ lnfg, const float* __restrict__ lnfb,
                        float2* c12q, float2* c12f, float2* c12lm) {
  const int t = blockIdx.x;
  const float* Wz; const float* gz; const float* bz; float2* outb; int N, nb;
  if (t < 108) {
    const int bx = t % 6, zy = t / 6, sel = zy / 6, l = zy % 6;
    Wz = (sel == 0 ? Wq : sel == 1 ? Wk : Wv) + (size_t)l * 147456;
    gz = ln1g + l * 384; bz = ln1b + l * 384;
    outb = c12q + (size_t)l * 1152 + sel * 384; N = 384; nb = bx << 6;
  } else if (t < 252) {
    const int t2 = t - 108, bx = t2 % 24, l = t2 / 24;
    Wz = W1 + (size_t)l * 589824;
    gz = ln2g + l * 384; bz = ln2b + l * 384;
    outb = c12f + (size_t)l * 1536; N = 1536; nb = bx << 6;
  } else {
    const int bx = t - 252;
    Wz = Wlm; gz = lnfg; bz = lnfb;
    outb = c12lm; N = 65; nb = bx << 6;
  }
  __shared__ float p1[4][64], p2[4][64];
  const int tt = threadIdx.x;
  const int c = tt & 63, kq = tt >> 6;
  const int n = nb + c;
  float s1 = 0.f, s2 = 0.f;
  if (n < N) {
    for (int k = kq * 96; k < kq * 96 + 96; ++k) {
      const float w = Wz[(size_t)k * N + n];
      s1 = fmaf(gz[k], w, s1);
      s2 = fmaf(bz[k], w, s2);
    }
  }
  p1[kq][c] = s1; p2[kq][c] = s2;
  __syncthreads();
  if (tt < 64 && nb + tt < N) {
    float2 o;
    o.x = p1[0][tt] + p1[1][tt] + p1[2][tt] + p1[3][tt];
    o.y = p2[0][tt] + p2[1][tt] + p2[2][tt] + p2[3][tt];
    outb[nb + tt] = o;
  }
}

// ---------------------------------------------------------------------------
// Async global->LDS staging of a ROWS x (CHPR*8 us) bf16 tile. LDS dest is
// linear; XOR chunk swizzle applied on the GLOBAL source side (rule #21).
// ---------------------------------------------------------------------------
template<int ROWS, int CHPR, int NTH>
__device__ __forceinline__ void stageG(const us* g, int rowUs, us* lds, int tid) {
#pragma unroll
  for (int j = 0; j < ROWS * CHPR / NTH; ++j) {
    const int fl  = j * NTH + tid;
    const int row = fl / CHPR;
    const int c   = fl % CHPR;
    const int gc  = (CHPR == 8) ? (c ^ (row & 7)) : (c ^ ((row >> 1) & 3));
    const us* src = g + (size_t)row * rowUs + gc * 8;
    __builtin_amdgcn_global_load_lds(
        (const __attribute__((address_space(1))) u32*)src,
        (__attribute__((address_space(3))) u32*)(lds + ((fl >> 6) << 9)),
        16, 0, 0);
  }
}

// ---------------------------------------------------------------------------
// Shared K-loop machinery: tile (FM*32)x(FN*32), BK=32, 4 waves (2x2),
// BUFS-buffer / (BUFS-1)-deep prefetch, counted vmcnt, raw s_barrier.
// T5: s_setprio(1) around the MFMA cluster.
// ---------------------------------------------------------------------------
#define GEMM_LOOP(K_, NT_)                                                        \
  const int NT = (NT_);                                                           \
  _Pragma("unroll")                                                               \
  for (int p = 0; p < BUFS - 1; ++p) {                                            \
    stageG<BM, 4, 256>(Abase + p * 32, (K_), As[p], tid);                         \
    stageG<BN, 4, 256>(Bbase + p * 32, (K_), Bs[p], tid);                         \
  }                                                                               \
  int cb = 0;                                                                     \
  for (int t = 0; t < NT; ++t) {                                                  \
    if constexpr (BUFS == 4) {                                                    \
      if (t < NT - 2)       asm volatile("s_waitcnt vmcnt(%0)" :: "n"(2 * LPS) : "memory"); \
      else if (t == NT - 2) asm volatile("s_waitcnt vmcnt(%0)" :: "n"(LPS) : "memory");     \
      else                  asm volatile("s_waitcnt vmcnt(0)" ::: "memory");      \
    } else {                                                                      \
      if (t < NT - 1)       asm volatile("s_waitcnt vmcnt(%0)" :: "n"(LPS) : "memory");     \
      else                  asm volatile("s_waitcnt vmcnt(0)" ::: "memory");      \
    }                                                                             \
    __builtin_amdgcn_s_barrier();                                                 \
    __builtin_amdgcn_sched_barrier(0);                                            \
    if (t + BUFS - 1 < NT) {                                                      \
      int ib = cb + (BUFS - 1); if (ib >= BUFS) ib -= BUFS;                       \
      stageG<BM, 4, 256>(Abase + (t + BUFS - 1) * 32, (K_), As[ib], tid);         \
      stageG<BN, 4, 256>(Bbase + (t + BUFS - 1) * 32, (K_), Bs[ib], tid);         \
    }                                                                             \
    short8 af[FM], bfr[FN];                                                       \
    _Pragma("unroll")                                                             \
    for (int mt = 0; mt < FM; ++mt) {                                             \
      const int row = wm + mt * 16 + fm;                                          \
      af[mt] = *(const short8*)(As[cb] + row * 32 + ((fg ^ ((row >> 1) & 3)) << 3)); \
    }                                                                             \
    _Pragma("unroll")                                                             \
    for (int nt = 0; nt < FN; ++nt) {                                             \
      const int row = wn + nt * 16 + fm;                                          \
      bfr[nt] = *(const short8*)(Bs[cb] + row * 32 + ((fg ^ ((row >> 1) & 3)) << 3)); \
    }                                                                             \
    __builtin_amdgcn_s_setprio(1);                                                \
    _Pragma("unroll")                                                             \
    for (int mt = 0; mt < FM; ++mt)                                               \
      _Pragma("unroll")                                                           \
      for (int nt = 0; nt < FN; ++nt)                                             \
        acc[mt][nt] = __builtin_amdgcn_mfma_f32_16x16x32_bf16(af[mt], bfr[nt], acc[mt][nt], 0, 0, 0); \
    __builtin_amdgcn_s_setprio(0);                                                \
    cb = (cb + 1 == BUFS) ? 0 : cb + 1;                                           \
  }

// ---------------------------------------------------------------------------
// Plain MFMA GEMM, epilogue = +bias +Res(bf16) -> bf16.  (proj, FF2)
// ---------------------------------------------------------------------------
template<int FM, int FN, int BUFS>
__global__ __launch_bounds__(256)
void gemm_mfma(const us* __restrict__ A, const us* __restrict__ Bt,
               const float* __restrict__ bias, const us* Res,
               us* __restrict__ O, int N, int K, int gx) {
  constexpr int BM = FM * 32, BN = FN * 32;
  constexpr int LPS = (BM + BN) * 4 / 256;
  __shared__ us As[BUFS][BM * 32];
  __shared__ us Bs[BUFS][BN * 32];
  const int tid = threadIdx.x;
  const int lid = xcd_swz(blockIdx.x, gridDim.x);
  const int bnI = lid % gx, bmI = lid / gx;
  const int bm = bmI * BM, bn = bnI * BN;
  const int wv = tid >> 6, ln = tid & 63;
  const int fm = ln & 15, fg = ln >> 4;
  const int wm = (wv >> 1) * (FM * 16), wn = (wv & 1) * (FN * 16);
  const us* Abase = A + (size_t)bm * K;
  const us* Bbase = Bt + (size_t)bn * K;

  f32x4 acc[FM][FN];
  const f32x4 zz = {0.f, 0.f, 0.f, 0.f};
#pragma unroll
  for (int i = 0; i < FM; ++i)
#pragma unroll
    for (int j = 0; j < FN; ++j) acc[i][j] = zz;

  GEMM_LOOP(K, K >> 5)

#pragma unroll
  for (int mt = 0; mt < FM; ++mt) {
#pragma unroll
    for (int nt = 0; nt < FN; ++nt) {
      const int col  = bn + wn + nt * 16 + fm;
      const int row0 = bm + wm + mt * 16 + fg * 4;
      const float bc = bias[col];
#pragma unroll
      for (int r = 0; r < 4; ++r) {
        const size_t idx = (size_t)(row0 + r) * N + col;
        O[idx] = f2bf(acc[mt][nt][r] + bc + bf2f(Res[idx]));
      }
    }
  }
}

// ---------------------------------------------------------------------------
// Folded-LN MFMA GEMM: A = raw h (bf16), Bt pre-scaled by g.
// out = inv*(acc - mu*c1[col]) + c2[col] (+bias).
// EPI: 0 = QKV split; 2 = +bias +ReLU; 3 = +bias, col<65 (LM head)
// ---------------------------------------------------------------------------
template<int FM, int FN, int EPI, int BUFS>
__global__ __launch_bounds__(256)
void gemm_fold(const us* __restrict__ A, const us* __restrict__ Bt,
               const float2* __restrict__ st, const float2* __restrict__ c12,
               const float* __restrict__ bias, void* O0, void* O1,
               int N, int gx) {
  constexpr int K = 384;
  constexpr int BM = FM * 32, BN = FN * 32;
  constexpr int LPS = (BM + BN) * 4 / 256;
  __shared__ us As[BUFS][BM * 32];
  __shared__ us Bs[BUFS][BN * 32];
  const int tid = threadIdx.x;
  const int lid = xcd_swz(blockIdx.x, gridDim.x);
  const int bnI = lid % gx, bmI = lid / gx;
  const int bm = bmI * BM, bn = bnI * BN;
  const int wv = tid >> 6, ln = tid & 63;
  const int fm = ln & 15, fg = ln >> 4;
  const int wm = (wv >> 1) * (FM * 16), wn = (wv & 1) * (FN * 16);
  const us* Abase = A + (size_t)bm * K;
  const us* Bbase = Bt + (size_t)bn * K;

  f32x4 acc[FM][FN];
  const f32x4 zz = {0.f, 0.f, 0.f, 0.f};
#pragma unroll
  for (int i = 0; i < FM; ++i)
#pragma unroll
    for (int j = 0; j < FN; ++j) acc[i][j] = zz;

  GEMM_LOOP(K, 12)

#pragma unroll
  for (int mt = 0; mt < FM; ++mt) {
    const int row0 = bm + wm + mt * 16 + fg * 4;
    float2 sr[4];
#pragma unroll
    for (int r = 0; r < 4; ++r) sr[r] = st[row0 + r];
#pragma unroll
    for (int nt = 0; nt < FN; ++nt) {
      const int col = bn + wn + nt * 16 + fm;
      if (EPI == 3 && col >= V_) continue;
      const float2 cc = c12[col];
      float vals[4];
#pragma unroll
      for (int r = 0; r < 4; ++r)
        vals[r] = sr[r].y * (acc[mt][nt][r] - sr[r].x * cc.x) + cc.y;
      if (EPI == 0) {
        if (col < 768) {
          us* qk = (us*)O0;
#pragma unroll
          for (int r = 0; r < 4; ++r)
            qk[(size_t)(row0 + r) * 768 + col] = f2bf(vals[r]);
        } else {                              // v -> transposed [B*H][64][256]
          const int d = col - 768;
          const int hh = d >> 6, dd = d & 63;
          const int bI = row0 >> 8, t0 = row0 & 255;
          us* vt = (us*)O1;
          ushort4 pk;
          pk.x = f2bf(vals[0]); pk.y = f2bf(vals[1]);
          pk.z = f2bf(vals[2]); pk.w = f2bf(vals[3]);
          *reinterpret_cast<ushort4*>(vt + ((size_t)((bI * H_ + hh) * 64 + dd)) * 256 + t0) = pk;
        }
      } else if (EPI == 2) {
        us* o = (us*)O0;
        const float bc = bias[col];
#pragma unroll
        for (int r = 0; r < 4; ++r)
          o[(size_t)(row0 + r) * N + col] = f2bf(fmaxf(vals[r] + bc, 0.f));
      } else {
        float* o = (float*)O0;
        const float bc = bias[col];
#pragma unroll
        for (int r = 0; r < 4; ++r)
          o[(size_t)(row0 + r) * V_ + col] = vals[r] + bc;
      }
    }
  }
}

// ---------------------------------------------------------------------------
// MFMA flash attention, work-balanced: block = (b, h, pair p); processes
// Q-tiles qt=p and qt=3-p sequentially -> every block does exactly 5 K-tile
// iterations. 4 waves x 16 queries. K/V LDS double-buffered, CHPR=8 swizzle.
// ---------------------------------------------------------------------------
__global__ __launch_bounds__(256)
void attn_mfma(const us* __restrict__ qk, const us* __restrict__ vT,
               us* __restrict__ ab) {
  __shared__ us Ks[2][64 * 64];
  __shared__ us Vs[2][64 * 64];
  __shared__ us Plds[4][16 * 72];   // per-wave P tile, stride 72 (pad)
  const int tid = threadIdx.x, w = tid >> 6, l = tid & 63;
  const int m = l & 15, g = l >> 4;
  const int bi = xcd_swz(blockIdx.x, gridDim.x);
  const int b = bi / 12, rem = bi - b * 12, h = rem >> 1, p = rem & 1;
  const us* Kg = qk + (size_t)(b << 8) * 768 + 384 + h * 64;  // + kt*64 rows
  const us* Vg = vT + (size_t)(b * H_ + h) * 64 * 256;        // + kt*64 cols

  int cur = 0;
  const f32x4 zz = {0.f, 0.f, 0.f, 0.f};

#pragma unroll
  for (int half = 0; half < 2; ++half) {
    const int qt = half == 0 ? p : 3 - p;
    const int qrow = (b << 8) + (qt << 6) + (w << 4);

    short8 qf0, qf1;
    {
      const us* qp = qk + (size_t)(qrow + m) * 768 + h * 64 + g * 8;
      qf0 = *(const short8*)qp;
      qf1 = *(const short8*)(qp + 32);
    }
    float mrow[4], ssum[4];
    f32x4 o[4];
#pragma unroll
    for (int r = 0; r < 4; ++r) { mrow[r] = -1e30f; ssum[r] = 0.f; o[r] = zz; }

    stageG<64, 8, 256>(Kg, 768, Ks[cur], tid);
    stageG<64, 8, 256>(Vg, 256, Vs[cur], tid);
    __syncthreads();

    for (int kt = 0; kt <= qt; ++kt) {
      if (kt < qt) {
        stageG<64, 8, 256>(Kg + (size_t)(kt + 1) * 64 * 768, 768, Ks[cur ^ 1], tid);
        stageG<64, 8, 256>(Vg + (kt + 1) * 64,               256, Vs[cur ^ 1], tid);
      }
      // ---- S = Q K^T (16 queries x 64 keys) from LDS ----
      f32x4 s[4];
      __builtin_amdgcn_s_setprio(1);
#pragma unroll
      for (int nt = 0; nt < 4; ++nt) {
        const int row = nt * 16 + m;
        const int sw  = row & 7;
        short8 kf0 = *(const short8*)(Ks[cur] + row * 64 + ((g ^ sw) << 3));
        short8 kf1 = *(const short8*)(Ks[cur] + row * 64 + (((4 | g) ^ sw) << 3));
        f32x4 z = zz;
        z = __builtin_amdgcn_mfma_f32_16x16x32_bf16(qf0, kf0, z, 0, 0, 0);
        z = __builtin_amdgcn_mfma_f32_16x16x32_bf16(qf1, kf1, z, 0, 0, 0);
        s[nt] = z;
      }
      __builtin_amdgcn_s_setprio(0);
      // ---- mask + online softmax ----
      const bool diag = (kt == qt);
      float pr[4][4], tmax[4];
#pragma unroll
      for (int r = 0; r < 4; ++r) tmax[r] = -1e30f;
#pragma unroll
      for (int nt = 0; nt < 4; ++nt)
#pragma unroll
        for (int r = 0; r < 4; ++r) {
          float v = s[nt][r] * 0.125f;
          if (diag) {
            const int key = nt * 16 + m;
            const int qq  = (w << 4) + (g << 2) + r;
            if (key > qq) v = -1e30f;
          }
          pr[nt][r] = v;
          tmax[r] = fmaxf(tmax[r], v);
        }
#pragma unroll
      for (int xm = 1; xm < 16; xm <<= 1)
#pragma unroll
        for (int r = 0; r < 4; ++r) tmax[r] = fmaxf(tmax[r], __shfl_xor(tmax[r], xm));
      float sc[4], tsum[4];
#pragma unroll
      for (int r = 0; r < 4; ++r) {
        const float nm = fmaxf(mrow[r], tmax[r]);
        sc[r] = __expf(mrow[r] - nm);
        mrow[r] = nm;
        tsum[r] = 0.f;
      }
#pragma unroll
      for (int nt = 0; nt < 4; ++nt)
#pragma unroll
        for (int r = 0; r < 4; ++r) {
          pr[nt][r] = __expf(pr[nt][r] - mrow[r]);
          tsum[r] += pr[nt][r];
        }
#pragma unroll
      for (int xm = 1; xm < 16; xm <<= 1)
#pragma unroll
        for (int r = 0; r < 4; ++r) tsum[r] += __shfl_xor(tsum[r], xm);
#pragma unroll
      for (int r = 0; r < 4; ++r) ssum[r] = ssum[r] * sc[r] + tsum[r];
#pragma unroll
      for (int nt = 0; nt < 4; ++nt)
#pragma unroll
        for (int r = 0; r < 4; ++r) o[nt][r] *= sc[r];
      // ---- P -> LDS (bf16, C-layout -> A-layout transpose via LDS) ----
#pragma unroll
      for (int nt = 0; nt < 4; ++nt)
#pragma unroll
        for (int r = 0; r < 4; ++r)
          Plds[w][(g * 4 + r) * 72 + nt * 16 + m] = f2bf(pr[nt][r]);
      // ---- O += P V (V from LDS) ----
      __builtin_amdgcn_s_setprio(1);
#pragma unroll
      for (int kc = 0; kc < 2; ++kc) {
        short8 pa = *(const short8*)&Plds[w][m * 72 + kc * 32 + g * 8];
#pragma unroll
        for (int nd = 0; nd < 4; ++nd) {
          const int row = nd * 16 + m;
          short8 vf = *(const short8*)(Vs[cur] + row * 64 + ((((kc << 2) | g) ^ (row & 7)) << 3));
          o[nd] = __builtin_amdgcn_mfma_f32_16x16x32_bf16(pa, vf, o[nd], 0, 0, 0);
        }
      }
      __builtin_amdgcn_s_setprio(0);
      __syncthreads();   // staged next tile arrived; all reads of cur done
      cur ^= 1;
    }
    // ---- normalize + write ----
#pragma unroll
    for (int r = 0; r < 4; ++r) {
      const float inv = 1.f / ssum[r];
      const size_t rowoff = (size_t)(qrow + g * 4 + r) * 384 + h * 64;
#pragma unroll
      for (int nd = 0; nd < 4; ++nd)
        ab[rowoff + nd * 16 + m] = f2bf(o[nd][r] * inv);
    }
  }
}

// ---------------------------------------------------------------------------
extern "C" void kernel_launch(void* const* d_in, const int* in_sizes, int n_in,
                              void* d_out, int out_size, void* d_ws, size_t ws_size,
                              hipStream_t stream) {
  const int*   x    = (const int*)  d_in[0];
  const float* tok  = (const float*)d_in[1];
  const float* pos  = (const float*)d_in[2];
  const float* Wq   = (const float*)d_in[3];
  const float* Wk   = (const float*)d_in[4];
  const float* Wv   = (const float*)d_in[5];
  const float* Wpr  = (const float*)d_in[6];
  const float* bpr  = (const float*)d_in[7];
  const float* W1   = (const float*)d_in[8];
  const float* b1   = (const float*)d_in[9];
  const float* W2   = (const float*)d_in[10];
  const float* b2   = (const float*)d_in[11];
  const float* ln1g = (const float*)d_in[12];
  const float* ln1b = (const float*)d_in[13];
  const float* ln2g = (const float*)d_in[14];
  const float* ln2b = (const float*)d_in[15];
  const float* lnfg = (const float*)d_in[16];
  const float* lnfb = (const float*)d_in[17];
  const float* Wlm  = (const float*)d_in[18];
  const float* blm  = (const float*)d_in[19];
  float* out = (float*)d_out;

  char* W = (char*)d_ws;
  us*     h    = (us*)(W + 0);            // [BT][384] bf16       12.58 MB
  us*     qkb  = (us*)(W + 12582912);     // [BT][768] bf16       25.17 MB
  us*     vTb  = (us*)(W + 37748736);     // [B*H][64][256] bf16  12.58 MB
  us*     abb  = (us*)(W + 50331648);     // [BT][384] bf16       12.58 MB
  us*     ffa  = (us*)(W + 12582912);     // [BT][1536] bf16 (aliases qk+vT+ab)
  us*     qkvT = (us*)(W + 62914560);     // [L][1152][384] bf16 (g-scaled)
  us*     projT= (us*)(W + 68222976);     // [L][384][384]
  us*     W1T  = (us*)(W + 69992448);     // [L][1536][384] (g-scaled)
  us*     W2T  = (us*)(W + 77070336);     // [L][384][1536]
  us*     WlmT = (us*)(W + 84148224);     // [128][384] (g-scaled, rows 65+ zero)
  float2* st   = (float2*)(W + 84246528); // [BT] (mean, inv)     131 KB
  float2* c12q = (float2*)(W + 84377600); // [L][1152]
  float2* c12f = (float2*)(W + 84432896); // [L][1536]
  float2* c12lm= (float2*)(W + 84506624); // [65]

  // ---- merged weight prep (all transposes) + merged c1/c2 ----
  prep_kernel<<<10416, 256, 0, stream>>>(Wq, Wk, Wv, Wpr, W1, W2, Wlm,
                                         qkvT, projT, W1T, W2T, WlmT,
                                         ln1g, ln2g, lnfg);
  c12_all<<<254, 256, 0, stream>>>(Wq, Wk, Wv, W1, Wlm,
                                   ln1g, ln1b, ln2g, ln2b, lnfg, lnfb,
                                   c12q, c12f, c12lm);

  embed_kernel<<<3072, 256, 0, stream>>>(x, tok, pos, h);

  for (int l = 0; l < L_; ++l) {
    stats_kernel<1><<<BT_/8, 512, 0, stream>>>(h, st);
    // QKV (folded LN1): 128x128 tiles, BUFS=3 -> 1152 blocks
    gemm_fold<4,4,0,3><<<1152, 256, 0, stream>>>(
        h, qkvT + (size_t)l*442368, st, c12q + (size_t)l*1152, nullptr,
        qkb, vTb, 1152, 9);
    // attention: balanced pairs -> 768 blocks (5 K-tiles each)
    attn_mfma<<<B_*H_*2, 256, 0, stream>>>(qkb, vTb, abb);
    // proj: 64x128 tiles, BUFS=4 -> 768 blocks
    gemm_mfma<2,4,4><<<768, 256, 0, stream>>>(
        abb, projT + (size_t)l*147456, bpr + l*E_, h, h, 384, 384, 3);
    stats_kernel<1><<<BT_/8, 512, 0, stream>>>(h, st);
    // FF1 (folded LN2): 128x128 tiles, BUFS=3 -> 1536 blocks
    gemm_fold<4,4,2,3><<<1536, 256, 0, stream>>>(
        h, W1T + (size_t)l*589824, st, c12f + (size_t)l*1536, b1 + l*FF_,
        ffa, nullptr, 1536, 12);
    // FF2: 64x128 tiles, K=1536, BUFS=4 -> 768 blocks
    gemm_mfma<2,4,4><<<768, 256, 0, stream>>>(
        ffa, W2T + (size_t)l*589824, b2 + l*E_, h, h, 384, 1536, 3);
  }

  stats_kernel<0><<<BT_/8, 512, 0, stream>>>(h, st);
  // LM head (folded LNf): 64x128 tiles, BUFS=3 -> 256 blocks
  gemm_fold<2,4,3,3><<<256, 256, 0, stream>>>(
      h, WlmT, st, c12lm, blm, out, nullptr, 128, 1);
}